// Round 12
// baseline (168.849 us; speedup 1.0000x reference)
//
#include <hip/hip_runtime.h>
#include <stdint.h>

// ---------------------------------------------------------------------------
// Problem constants
// ---------------------------------------------------------------------------
#define NSEQ 512        // B*N
#define HIDN 128

// ws byte offsets
#define OFF_PWIH_E 0                            // 32*512*4 = 65536 (gx weights)
#define OFF_BIAS_E 65536                        // 512 f32
#define OFF_BIAS_D 67584                        // 512 f32
#define OFF_W1P    69632                        // conv w1 f16 pairs [288][64]
#define OFF_W2P    143360                       // conv w2 f16 pairs [32][64]
#define OFF_FLAT   151552                       // [16384] int
#define OFF_W1H    217088                       // head W1 f16 pairs [64][64]
#define OFF_FEHH   233472                       // enc Whh f16 frags, 128 KB
#define OFF_FDIH8  364544                       // dec Wih fp8 frags, 64 KB
#define OFF_FDHH8  430080                       // dec Whh fp8 frags, 64 KB
#define OFF_DOTS   (1024*1024)                  // [32][512][64] f16 = 2 MB
#define OFF_GX_FB  (3*1024*1024)                // fallback gx area
#define OFF_XT     (4*1024*1024)                // xT f16 = 33.5 MB (gx overlays)
#define WS_NEED_XT ((size_t)(4*1024*1024) + (size_t)16*128*128*64*2 + 1024)

typedef _Float16 h2f __attribute__((ext_vector_type(2)));
typedef _Float16 f16x8 __attribute__((ext_vector_type(8)));
typedef float    f32x4 __attribute__((ext_vector_type(4)));

static __device__ __forceinline__ h2f u2h(uint32_t u) {
  union { uint32_t u; h2f h; } v; v.u = u; return v.h;
}

#if __has_builtin(__builtin_amdgcn_fdot2)
static __device__ __forceinline__ float fdot2_(uint32_t a, uint32_t b, float c) {
  return __builtin_amdgcn_fdot2(u2h(a), u2h(b), c, false);
}
#else
static __device__ __forceinline__ float fdot2_(uint32_t a, uint32_t b, float c) {
  h2f x = u2h(a), y = u2h(b);
  return c + (float)x.x * (float)y.x + (float)x.y * (float)y.y;
}
#endif

static __device__ __forceinline__ uint32_t packh(float a, float b) {
  union { _Float16 h[2]; uint32_t u; } v;
  v.h[0] = (_Float16)a; v.h[1] = (_Float16)b; return v.u;
}
static __device__ __forceinline__ float sig_(float x) {
  return 1.0f / (1.0f + __expf(-x));
}
static __device__ __forceinline__ float tanh_(float x) {
  return 1.0f - 2.0f / (1.0f + __expf(2.0f * x));
}

// ---- fp8 e4m3fn helpers ----------------------------------------------------
static __device__ __forceinline__ uint32_t f2e4m3_sw(float f) {
  union { float f; uint32_t u; } v; v.f = f;
  uint32_t s = (v.u >> 24) & 0x80u;
  float af = fabsf(f);
  if (af == 0.0f) return s;
  if (af >= 448.0f) return s | 0x7Eu;
  int e; float m = frexpf(af, &e);      // af = m*2^e, m in [0.5,1)
  int E = e + 6;                         // 1.xxx*2^(e-1), bias 7
  float mant = m * 2.0f - 1.0f;
  int mm = (int)(mant * 8.0f + 0.5f);
  if (mm == 8) { mm = 0; ++E; }
  if (E < 1) {                           // subnormal: step 2^-9
    int sm = (int)(af * 512.0f + 0.5f);
    return s | (uint32_t)(sm > 7 ? 7 : sm);
  }
  if (E > 15) return s | 0x7Eu;
  return s | ((uint32_t)E << 3) | (uint32_t)mm;
}
static __device__ __forceinline__ uint32_t pk4_fp8(float a, float b, float c, float d) {
#if __has_builtin(__builtin_amdgcn_cvt_pk_fp8_f32)
  int r = __builtin_amdgcn_cvt_pk_fp8_f32(a, b, 0, false);
  r = __builtin_amdgcn_cvt_pk_fp8_f32(c, d, r, true);
  return (uint32_t)r;
#else
  return f2e4m3_sw(a) | (f2e4m3_sw(b) << 8) | (f2e4m3_sw(c) << 16) | (f2e4m3_sw(d) << 24);
#endif
}
static __device__ __forceinline__ uint8_t f8_(float v) {
#if __has_builtin(__builtin_amdgcn_cvt_pk_fp8_f32)
  return (uint8_t)(__builtin_amdgcn_cvt_pk_fp8_f32(v, 0.f, 0, false) & 0xFF);
#else
  return (uint8_t)f2e4m3_sw(v);
#endif
}
static __device__ __forceinline__ long u2l(uint2 v) {
  union { uint2 v; long l; } x; x.v = v; return x.l;
}
// pinned 8B load (asm-produced -> non-rematerializable)
static __device__ __forceinline__ uint2 ldg_frag8(const uint2* p) {
  uint2 r;
  asm volatile("global_load_dwordx2 %0, %1, off" : "=v"(r) : "v"(p));
  return r;
}
static __device__ __forceinline__ void frag_fence() {
  asm volatile("s_waitcnt vmcnt(0)" ::: "memory");
  __builtin_amdgcn_sched_barrier(0);
}

// ---------------------------------------------------------------------------
// Kernel 0: weight prep + point math.
// f16 A-frag (16x16x32): lane l holds A[row=l&15][k=(l>>4)*8+j], j=0..7.
// PLAIN tiling: g = gt*16 + (l&15); k = kt*32 + ((l>>4)&3)*8 + ...
// fp8 frags use the same map with 8 fp8 bytes (2 VGPRs).
// ---------------------------------------------------------------------------
__global__ __launch_bounds__(256) void prep_kernel(
    const float* Wih_e, const float* Whh_e,
    const float* bih_e, const float* bhh_e,
    const float* Wih_d, const float* Whh_d,
    const float* bih_d, const float* bhh_d,
    const float* w1, const float* w2, const float* W1,
    const float* mask_point, float* out_gt, int* flat,
    char* ws, int w1_order) {
  uint32_t* pWih_e = (uint32_t*)(ws + OFF_PWIH_E);
  float*    bias_e = (float*)(ws + OFF_BIAS_E);
  float*    bias_d = (float*)(ws + OFF_BIAS_D);
  uint32_t* w1p    = (uint32_t*)(ws + OFF_W1P);
  uint32_t* w2p    = (uint32_t*)(ws + OFF_W2P);
  uint32_t* W1h    = (uint32_t*)(ws + OFF_W1H);

  int idx = blockIdx.x * 256 + threadIdx.x;
  if (idx < 32*512) {                             // pWih_e [k2][g] (for gx)
    int k2 = idx >> 9, g = idx & 511;
    pWih_e[idx] = packh(Wih_e[g*64 + 2*k2], Wih_e[g*64 + 2*k2 + 1]);
    return;
  }
  idx -= 32*512;
  if (idx < 512) { bias_e[idx] = bih_e[idx] + bhh_e[idx]; return; }
  idx -= 512;
  if (idx < 512) { bias_d[idx] = bih_d[idx] + bhh_d[idx]; return; }
  idx -= 512;
  if (idx < 288*64) {                             // conv w1 pairs [i2][c]
    int i2 = idx >> 6, c = idx & 63;
    if (w1_order) {
      int tap = i2 >> 5, cin = (i2 & 31) * 2;     // i2 = tap*32 + c2
      w1p[idx] = packh(w1[c*576 + cin*9 + tap], w1[c*576 + (cin+1)*9 + tap]);
    } else {
      w1p[idx] = packh(w1[c*576 + 2*i2], w1[c*576 + 2*i2 + 1]);
    }
    return;
  }
  idx -= 288*64;
  if (idx < 32*64) {                              // conv w2 pairs [c2][d]
    int c2 = idx >> 6, d = idx & 63;
    w2p[idx] = packh(w2[d*64 + 2*c2], w2[d*64 + 2*c2 + 1]);
    return;
  }
  idx -= 32*64;
  if (idx < 64*64) {                              // head W1 pairs [k2][j]
    int k2 = idx >> 6, j = idx & 63;
    W1h[idx] = packh(W1[j*128 + 2*k2], W1[j*128 + 2*k2 + 1]);
    return;
  }
  idx -= 64*64;
  if (idx < 32768) {                              // fehh f16 frags
    int j2 = idx & 3, lane = (idx >> 2) & 63, kt = (idx >> 8) & 3, gt = idx >> 10;
    int g = gt*16 + (lane & 15);
    int k = kt*32 + ((lane >> 4) & 3)*8 + 2*j2;
    ((uint32_t*)(ws + OFF_FEHH))[idx] = packh(Whh_e[g*128 + k], Whh_e[g*128 + k + 1]);
    return;
  }
  idx -= 32768;
  if (idx < 16384) {                              // fdih8 fp8 frags
    int half = idx & 1, lane = (idx >> 1) & 63, kt = (idx >> 7) & 3, gt = idx >> 9;
    int g = gt*16 + (lane & 15);
    int kb = kt*32 + ((lane >> 4) & 3)*8 + half*4;
    const float* W = Wih_d;
    ((uint32_t*)(ws + OFF_FDIH8))[(((gt*4 + kt)*64 + lane) << 1) | half] =
        pk4_fp8(W[g*128 + kb], W[g*128 + kb + 1], W[g*128 + kb + 2], W[g*128 + kb + 3]);
    return;
  }
  idx -= 16384;
  if (idx < 16384) {                              // fdhh8 fp8 frags
    int half = idx & 1, lane = (idx >> 1) & 63, kt = (idx >> 7) & 3, gt = idx >> 9;
    int g = gt*16 + (lane & 15);
    int kb = kt*32 + ((lane >> 4) & 3)*8 + half*4;
    const float* W = Whh_d;
    ((uint32_t*)(ws + OFF_FDHH8))[(((gt*4 + kt)*64 + lane) << 1) | half] =
        pk4_fp8(W[g*128 + kb], W[g*128 + kb + 1], W[g*128 + kb + 2], W[g*128 + kb + 3]);
    return;
  }
  idx -= 16384;
  if (idx < 16384) {                              // point math -> gt + flat
    float mx = mask_point[idx*2 + 0];
    float my = mask_point[idx*2 + 1];
    float fx = fminf(mx * 0.25f, 127.0f);
    float fy = fminf(my * 0.25f, 127.0f);
    out_gt[idx*2 + 0] = fx * 4.0f;
    out_gt[idx*2 + 1] = fy * 4.0f;
    flat[idx] = (int)(__fmaf_rn(fy, 128.0f, fx)); // fy*128 exact
    return;
  }
}
#define PREP_TOTAL (32*512 + 512 + 512 + 288*64 + 32*64 + 64*64 + 32768 + 16384 + 16384 + 16384)

// ---------------------------------------------------------------------------
// Kernel T: x [16][64][128][128] f32 -> xT [16][128][128][64] f16 (NHWC)
// ---------------------------------------------------------------------------
__global__ __launch_bounds__(256, 2) void transpose_kernel(
    const float* x, uint32_t* xT32) {
  __shared__ float lds[64][257];
  int bid = blockIdx.x;           // 1024 = 16 b x 16 yt x 4 xt
  int xt = bid & 3, yt = (bid >> 2) & 15, b = bid >> 6;
  int x0 = xt * 32, y0 = yt * 8;
  int tx = threadIdx.x & 31, ty = threadIdx.x >> 5;
  #pragma unroll 8
  for (int c = 0; c < 64; ++c)
    lds[c][ty*32 + tx] = x[((b*64 + c)*128 + (y0 + ty))*128 + (x0 + tx)];
  __syncthreads();
  #pragma unroll 8
  for (int r = 0; r < 32; ++r) {
    int i = threadIdx.x + 256*r;    // i = pos*32 + c2
    int c2 = i & 31, pos = i >> 5;
    int yy = pos >> 5, xx = pos & 31;
    float lo = lds[2*c2][yy*32 + xx], hi = lds[2*c2 + 1][yy*32 + xx];
    xT32[((b*128 + y0 + yy)*128 + (x0 + xx))*32 + c2] = packh(lo, hi);
  }
}

// ---------------------------------------------------------------------------
// Kernel 2: fused gathered conv (3x3 -> ReLU -> 1x1) at points, 4 pts/group
// ---------------------------------------------------------------------------
template <int MODE>
__global__ __launch_bounds__(256, 2) void conv_gather_kernel(
    const float* x, const uint32_t* xT32, const int* point_mask,
    const float* conv1_b, const float* conv2_b,
    const char* ws_ro, _Float16* dots_h, const int* flat) {
  __shared__ uint32_t w1s[64*292];    // 74752 B
  __shared__ uint32_t patch2[4*288];  //  4608 B
  __shared__ uint32_t tl2[4*32];      //   512 B

  const uint32_t* w1p = (const uint32_t*)(ws_ro + OFF_W1P);
  const uint32_t* w2p = (const uint32_t*)(ws_ro + OFF_W2P);
  int tid = threadIdx.x;
  for (int i = tid; i < 288*64; i += 256) {
    int i2 = i >> 6, cc = i & 63;
    w1s[cc*292 + i2] = w1p[i];
  }

  int q = tid >> 6, c = tid & 63;
  float c1b = conv1_b[c], c2b = conv2_b[c];

  for (int g = 0; g < 8; ++g) {
    int p0 = blockIdx.x * 32 + g * 4;
    __syncthreads();
    if (MODE == 1) {
      #pragma unroll
      for (int r = 0; r < 5; ++r) {  // 1152 u32 = 4 pts x 288
        int u = tid + 256*r;
        if (u < 1152) {
          int slot = u / 288, w = u - slot*288;
          int tap = w >> 5, c2i = w & 31;
          int p = p0 + slot;
          int fl = flat[p];
          int hh = fl >> 7, ww = fl & 127;
          int b = p >> 10;
          int dy = tap / 3, dx = tap - dy*3;
          int yy = hh + dy - 1, xx = ww + dx - 1;
          uint32_t v = 0u;
          if (yy >= 0 && yy < 128 && xx >= 0 && xx < 128)
            v = xT32[((b*128 + yy)*128 + xx)*32 + c2i];
          patch2[slot*288 + w] = v;
        }
      }
    } else {
      #pragma unroll
      for (int r = 0; r < 9; ++r) {  // 2304 halves = 4 pts x 576
        int l = tid + 256*r;
        int slot = l / 576;
        int within = l - slot*576;
        int cp = within / 9;
        int tap = within - cp*9;
        int p = p0 + slot;
        int fl = flat[p];
        int hh = fl >> 7, ww = fl & 127;
        int b = p >> 10;
        int yy = hh + tap/3 - 1, xx = ww + tap%3 - 1;
        float v = 0.0f;
        if (yy >= 0 && yy < 128 && xx >= 0 && xx < 128)
          v = x[((b*64 + cp)*128 + yy)*128 + xx];
        ((_Float16*)patch2)[l] = (_Float16)v;
      }
    }
    __syncthreads();

    float a0 = c1b, a1 = 0.f, a2 = 0.f, a3 = 0.f;
    int cbase = c * 292, pbase = q * 288;
    #pragma unroll 4
    for (int i2 = 0; i2 < 288; i2 += 4) {
      a0 = fdot2_(w1s[cbase + i2+0], patch2[pbase + i2+0], a0);
      a1 = fdot2_(w1s[cbase + i2+1], patch2[pbase + i2+1], a1);
      a2 = fdot2_(w1s[cbase + i2+2], patch2[pbase + i2+2], a2);
      a3 = fdot2_(w1s[cbase + i2+3], patch2[pbase + i2+3], a3);
    }
    float t1 = fmaxf((a0 + a1) + (a2 + a3), 0.0f);
    ((_Float16*)tl2)[q*64 + c] = (_Float16)t1;
    // tl2[q] written/read by same wave -> no barrier

    float acc2 = c2b;
    #pragma unroll
    for (int c2i = 0; c2i < 32; ++c2i)
      acc2 = fdot2_(w2p[c2i*64 + c], tl2[q*32 + c2i], acc2);
    int p = p0 + q;
    acc2 *= (float)point_mask[p];
    int k = p & 31, bn = p >> 5;
    dots_h[(k*NSEQ + bn)*64 + c] = (_Float16)acc2;   // time-major [k][bn][d]
  }
}

// ---------------------------------------------------------------------------
// Kernel G: encoder x-projection GEMM: gx[R][g] = bias_e[g] + Wih_e . dots[R]
// ---------------------------------------------------------------------------
__global__ __launch_bounds__(512, 4) void gx_gemm_kernel(
    const char* ws_ro, _Float16* gx) {
  const uint32_t* pWih_e = (const uint32_t*)(ws_ro + OFF_PWIH_E);
  const float*    bias_e = (const float*)(ws_ro + OFF_BIAS_E);
  const uint32_t* dots_u = (const uint32_t*)(ws_ro + OFF_DOTS);
  __shared__ uint32_t xs[32][32];   // 4 KB
  int tid = threadIdx.x;
  int R0 = blockIdx.x * 32;
  for (int i = tid; i < 32*32; i += 512)
    xs[i >> 5][i & 31] = dots_u[(R0 + (i >> 5))*32 + (i & 31)];
  uint32_t wv[32];
  #pragma unroll
  for (int k = 0; k < 32; ++k) wv[k] = pWih_e[k*512 + tid];
  float bs = bias_e[tid];
  __syncthreads();
  #pragma unroll 2
  for (int r = 0; r < 32; ++r) {
    float a = bs;
    #pragma unroll
    for (int k = 0; k < 32; ++k) a = fdot2_(wv[k], xs[r][k], a);
    gx[(size_t)(R0 + r)*512 + tid] = (_Float16)a;
  }
}

// ---------------------------------------------------------------------------
// Kernel 3: recurrent LSTMs via MFMA + fused MLP head. ONE SEQ PER BLOCK:
// 512 blocks x 512 threads (8 waves) -> 2 co-resident blocks/CU so the two
// independent recurrences fill each other's barrier/nonlin bubbles.
// Wave w owns gate-tiles gt = 4w..4w+3. B operand is broadcast (all 16 cols
// = the sequence's h) -> conflict-free LDS reads; C col 0 is the output.
// Encoder f16 MFMA + gx (1-step register prefetch); decoder fp8 MFMA.
// ---------------------------------------------------------------------------
__global__ __launch_bounds__(512, 4) void lstm_head_kernel(
    const char* ws_ro, const _Float16* gx,
    const float* b1, const float* W2, const float* b2,
    float* out_kp) {
  const f16x8* fehh   = (const f16x8*)(ws_ro + OFF_FEHH);
  const uint2* fdih8  = (const uint2*)(ws_ro + OFF_FDIH8);
  const uint2* fdhh8  = (const uint2*)(ws_ro + OFF_FDHH8);
  const float* bias_d = (const float*)(ws_ro + OFF_BIAS_D);
  const uint32_t* W1h = (const uint32_t*)(ws_ro + OFF_W1H);

  __shared__ __attribute__((aligned(16))) uint32_t enc8[32][32];   // 4 KB fp8
  __shared__ __attribute__((aligned(16))) uint32_t dech2[32][64];  // 8 KB f16
  __shared__ __attribute__((aligned(16))) uint32_t hb2[64];        // 256 B f16
  __shared__ __attribute__((aligned(16))) uint32_t hb8[32];        // 128 B fp8
  __shared__ __attribute__((aligned(16))) float    gb[512];        // 2 KB
  __shared__ float hidf[32][65];                                   // 8.3 KB

  int tid  = threadIdx.x;
  int lane = tid & 63, wave = tid >> 6;
  int col  = lane & 15, lgrp = lane >> 4;
  int bn   = blockIdx.x;                    // one sequence

  float c_reg = 0.0f;

  // encoder h-weights as f16 MFMA fragments (16 frags)
  f16x8 ae[4][4];
  #pragma unroll
  for (int g0 = 0; g0 < 4; ++g0)
    #pragma unroll
    for (int kt = 0; kt < 4; ++kt)
      ae[g0][kt] = fehh[((wave*4 + g0)*4 + kt)*64 + lane];

  if (tid < 64) hb2[tid] = 0u;

  // gx prefetch for t=0 (nonlin threads only)
  float cxi = 0.f, cxf = 0.f, cxg = 0.f, cxo = 0.f;
  if (tid < 128) {
    const _Float16* gr = gx + (size_t)(0*512 + bn)*512;
    cxi = (float)gr[tid];       cxf = (float)gr[128 + tid];
    cxg = (float)gr[256 + tid]; cxo = (float)gr[384 + tid];
  }
  __syncthreads();

  // ----------------- encoder -----------------
  for (int t = 0; t < 32; ++t) {
    // issue next step's gx loads (consumed next iteration -> full-step cover)
    float nxi = 0.f, nxf = 0.f, nxg = 0.f, nxo = 0.f;
    {
      int tn = (t + 1 < 32) ? t + 1 : t;
      if (tid < 128) {
        const _Float16* gr = gx + (size_t)(tn*512 + bn)*512;
        nxi = (float)gr[tid];       nxf = (float)gr[128 + tid];
        nxg = (float)gr[256 + tid]; nxo = (float)gr[384 + tid];
      }
    }
    f16x8 bf[4];
    #pragma unroll
    for (int kt = 0; kt < 4; ++kt)
      bf[kt] = *(const f16x8*)&hb2[kt*16 + lgrp*4];   // broadcast read
    __builtin_amdgcn_s_setprio(1);
    #pragma unroll
    for (int g0 = 0; g0 < 4; ++g0) {
      f32x4 acc = {0.f, 0.f, 0.f, 0.f};
      #pragma unroll
      for (int kt = 0; kt < 4; ++kt)
        acc = __builtin_amdgcn_mfma_f32_16x16x32_f16(ae[g0][kt], bf[kt], acc, 0, 0, 0);
      if (col == 0)
        *(f32x4*)&gb[(wave*4 + g0)*16 + lgrp*4] = acc;
    }
    __builtin_amdgcn_s_setprio(0);
    __syncthreads();
    if (tid < 128) {
      float ig = sig_ (gb[tid]       + cxi);
      float fg = sig_ (gb[128 + tid] + cxf);
      float gg = tanh_(gb[256 + tid] + cxg);
      float og = sig_ (gb[384 + tid] + cxo);
      c_reg = fg * c_reg + ig * gg;
      float hh = og * tanh_(c_reg);
      ((_Float16*)hb2)[tid] = (_Float16)hh;      // enc recurrence (f16)
      ((uint8_t*)&enc8[t][0])[tid] = f8_(hh);    // dec consumption (fp8)
    }
    cxi = nxi; cxf = nxf; cxg = nxg; cxo = nxo;
    __syncthreads();
  }

  // ---- transition: dec recurrent h (fp8) = enc final h ----
  if (tid < 128) {
    float hv = (float)((_Float16*)hb2)[tid];
    ((uint8_t*)hb8)[tid] = f8_(hv);
  }

  // ---- decoder weights: 32 asm-pinned fp8 frags ----
  uint2 dih8[4][4], dhh8[4][4];
  #pragma unroll
  for (int g0 = 0; g0 < 4; ++g0)
    #pragma unroll
    for (int kt = 0; kt < 4; ++kt) {
      dih8[g0][kt] = ldg_frag8(&fdih8[((wave*4 + g0)*4 + kt)*64 + lane]);
      dhh8[g0][kt] = ldg_frag8(&fdhh8[((wave*4 + g0)*4 + kt)*64 + lane]);
    }
  frag_fence();
  float bdi = 0.f, bdf = 0.f, bdg = 0.f, bdo = 0.f;
  if (tid < 128) {
    bdi = bias_d[tid];       bdf = bias_d[128 + tid];
    bdg = bias_d[256 + tid]; bdo = bias_d[384 + tid];
  }
  __syncthreads();

  // ----------------- decoder (fp8 MFMA) -----------------
  for (int t = 0; t < 32; ++t) {
    long bx[4], bh[4];
    #pragma unroll
    for (int kt = 0; kt < 4; ++kt) {
      bx[kt] = u2l(*(const uint2*)&enc8[t][kt*8 + lgrp*2]);  // broadcast
      bh[kt] = u2l(*(const uint2*)&hb8[kt*8 + lgrp*2]);      // broadcast
    }
    __builtin_amdgcn_s_setprio(1);
    #pragma unroll
    for (int g0 = 0; g0 < 4; ++g0) {
      f32x4 acc = {0.f, 0.f, 0.f, 0.f};
      #pragma unroll
      for (int kt = 0; kt < 4; ++kt)
        acc = __builtin_amdgcn_mfma_f32_16x16x32_fp8_fp8(
            u2l(dih8[g0][kt]), bx[kt], acc, 0, 0, 0);
      #pragma unroll
      for (int kt = 0; kt < 4; ++kt)
        acc = __builtin_amdgcn_mfma_f32_16x16x32_fp8_fp8(
            u2l(dhh8[g0][kt]), bh[kt], acc, 0, 0, 0);
      if (col == 0)
        *(f32x4*)&gb[(wave*4 + g0)*16 + lgrp*4] = acc;
    }
    __builtin_amdgcn_s_setprio(0);
    __syncthreads();
    if (tid < 128) {
      float ig = sig_ (gb[tid]       + bdi);
      float fg = sig_ (gb[128 + tid] + bdf);
      float gg = tanh_(gb[256 + tid] + bdg);
      float og = sig_ (gb[384 + tid] + bdo);
      c_reg = fg * c_reg + ig * gg;
      float hh = og * tanh_(c_reg);
      ((uint8_t*)hb8)[tid] = f8_(hh);                 // dec recurrence
      ((_Float16*)&dech2[t][0])[tid] = (_Float16)hh;  // head input (f16)
    }
    __syncthreads();
  }

  // ----------------- fused head: relu(dec@W1.T+b1)@W2.T+b2 ----------------
  {
    int j = tid & 63, w = tid >> 6;       // 8 waves; rows t = w + 8*m (32 rows)
    float acc[4];
    #pragma unroll
    for (int m = 0; m < 4; ++m) acc[m] = b1[j];
    #pragma unroll 8
    for (int k = 0; k < 64; ++k) {
      uint32_t wv = W1h[k*64 + j];
      #pragma unroll
      for (int m = 0; m < 4; ++m)
        acc[m] = fdot2_(wv, dech2[w + 8*m][k], acc[m]);
    }
    #pragma unroll
    for (int m = 0; m < 4; ++m)
      hidf[w + 8*m][j] = fmaxf(acc[m], 0.0f);
  }
  __syncthreads();
  if (tid < 64) {
    int t = tid >> 1, e = tid & 1;
    float acc = b2[e];
    #pragma unroll 16
    for (int j = 0; j < 64; ++j) acc += W2[e*64 + j] * hidf[t][j];
    out_kp[(bn*32 + t)*2 + e] = acc;
  }
}

// ---------------------------------------------------------------------------
// Launch
// ---------------------------------------------------------------------------
extern "C" void kernel_launch(void* const* d_in, const int* in_sizes, int n_in,
                              void* d_out, int out_size, void* d_ws, size_t ws_size,
                              hipStream_t stream) {
  const float* x          = (const float*)d_in[0];
  const float* mask_point = (const float*)d_in[1];
  const int*   point_mask = (const int*)d_in[2];
  const float* conv1_w    = (const float*)d_in[3];
  const float* conv1_b    = (const float*)d_in[4];
  const float* conv2_w    = (const float*)d_in[5];
  const float* conv2_b    = (const float*)d_in[6];
  const float* Wih_e      = (const float*)d_in[7];
  const float* Whh_e      = (const float*)d_in[8];
  const float* bih_e      = (const float*)d_in[9];
  const float* bhh_e      = (const float*)d_in[10];
  const float* Wih_d      = (const float*)d_in[11];
  const float* Whh_d      = (const float*)d_in[12];
  const float* bih_d      = (const float*)d_in[13];
  const float* bhh_d      = (const float*)d_in[14];
  const float* W1         = (const float*)d_in[15];
  const float* b1         = (const float*)d_in[16];
  const float* W2         = (const float*)d_in[17];
  const float* b2         = (const float*)d_in[18];

  float* out = (float*)d_out;
  char*  ws  = (char*)d_ws;

  const bool use_xt = (ws_size >= WS_NEED_XT);
  // gx overlays the xT region (dead after conv_gather); fallback otherwise
  _Float16* gx = (_Float16*)(ws + (use_xt ? OFF_XT : OFF_GX_FB));

  prep_kernel<<<(PREP_TOTAL + 255)/256, 256, 0, stream>>>(
      Wih_e, Whh_e, bih_e, bhh_e, Wih_d, Whh_d, bih_d, bhh_d,
      conv1_w, conv2_w, W1, mask_point, out + 32768, (int*)(ws + OFF_FLAT),
      ws, use_xt ? 1 : 0);

  if (use_xt) {
    transpose_kernel<<<1024, 256, 0, stream>>>(x, (uint32_t*)(ws + OFF_XT));
    conv_gather_kernel<1><<<512, 256, 0, stream>>>(
        x, (const uint32_t*)(ws + OFF_XT), point_mask, conv1_b, conv2_b,
        ws, (_Float16*)(ws + OFF_DOTS), (const int*)(ws + OFF_FLAT));
  } else {
    conv_gather_kernel<0><<<512, 256, 0, stream>>>(
        x, nullptr, point_mask, conv1_b, conv2_b,
        ws, (_Float16*)(ws + OFF_DOTS), (const int*)(ws + OFF_FLAT));
  }

  gx_gemm_kernel<<<512, 512, 0, stream>>>(ws, gx);

  lstm_head_kernel<<<512, 512, 0, stream>>>(ws, gx, b1, W2, b2, out);
}

// Round 13
// 159.760 us; speedup vs baseline: 1.0569x; 1.0569x over previous
//
#include <hip/hip_runtime.h>
#include <stdint.h>

// ---------------------------------------------------------------------------
// Problem constants
// ---------------------------------------------------------------------------
#define NSEQ 512        // B*N
#define HIDN 128

// ws byte offsets
#define OFF_PWIH_E 0                            // 32*512*4 = 65536 (gx weights)
#define OFF_BIAS_E 65536                        // 512 f32
#define OFF_BIAS_D 67584                        // 512 f32
#define OFF_W1P    69632                        // conv w1 f16 pairs [288][64]
#define OFF_W2P    143360                       // conv w2 f16 pairs [32][64]
#define OFF_FLAT   151552                       // [16384] int
#define OFF_W1H    217088                       // head W1 f16 pairs [64][64]
#define OFF_FEHH   233472                       // enc Whh f16 frags, 128 KB
#define OFF_FDIH8  364544                       // dec Wih fp8 frags, 64 KB
#define OFF_FDHH8  430080                       // dec Whh fp8 frags, 64 KB
#define OFF_DOTS   (1024*1024)                  // [32][512][64] f16 = 2 MB
#define OFF_GX_FB  (3*1024*1024)                // fallback gx area
#define OFF_XT     (4*1024*1024)                // xT f16 = 33.5 MB (gx overlays)
#define WS_NEED_XT ((size_t)(4*1024*1024) + (size_t)16*128*128*64*2 + 1024)

typedef _Float16 h2f __attribute__((ext_vector_type(2)));
typedef _Float16 f16x8 __attribute__((ext_vector_type(8)));
typedef float    f32x4 __attribute__((ext_vector_type(4)));

static __device__ __forceinline__ h2f u2h(uint32_t u) {
  union { uint32_t u; h2f h; } v; v.u = u; return v.h;
}

#if __has_builtin(__builtin_amdgcn_fdot2)
static __device__ __forceinline__ float fdot2_(uint32_t a, uint32_t b, float c) {
  return __builtin_amdgcn_fdot2(u2h(a), u2h(b), c, false);
}
#else
static __device__ __forceinline__ float fdot2_(uint32_t a, uint32_t b, float c) {
  h2f x = u2h(a), y = u2h(b);
  return c + (float)x.x * (float)y.x + (float)x.y * (float)y.y;
}
#endif

static __device__ __forceinline__ uint32_t packh(float a, float b) {
  union { _Float16 h[2]; uint32_t u; } v;
  v.h[0] = (_Float16)a; v.h[1] = (_Float16)b; return v.u;
}
static __device__ __forceinline__ float sig_(float x) {
  return 1.0f / (1.0f + __expf(-x));
}
static __device__ __forceinline__ float tanh_(float x) {
  return 1.0f - 2.0f / (1.0f + __expf(2.0f * x));
}

// ---- fp8 e4m3fn helpers ----------------------------------------------------
static __device__ __forceinline__ uint32_t f2e4m3_sw(float f) {
  union { float f; uint32_t u; } v; v.f = f;
  uint32_t s = (v.u >> 24) & 0x80u;
  float af = fabsf(f);
  if (af == 0.0f) return s;
  if (af >= 448.0f) return s | 0x7Eu;
  int e; float m = frexpf(af, &e);      // af = m*2^e, m in [0.5,1)
  int E = e + 6;                         // 1.xxx*2^(e-1), bias 7
  float mant = m * 2.0f - 1.0f;
  int mm = (int)(mant * 8.0f + 0.5f);
  if (mm == 8) { mm = 0; ++E; }
  if (E < 1) {                           // subnormal: step 2^-9
    int sm = (int)(af * 512.0f + 0.5f);
    return s | (uint32_t)(sm > 7 ? 7 : sm);
  }
  if (E > 15) return s | 0x7Eu;
  return s | ((uint32_t)E << 3) | (uint32_t)mm;
}
static __device__ __forceinline__ uint32_t pk4_fp8(float a, float b, float c, float d) {
#if __has_builtin(__builtin_amdgcn_cvt_pk_fp8_f32)
  int r = __builtin_amdgcn_cvt_pk_fp8_f32(a, b, 0, false);
  r = __builtin_amdgcn_cvt_pk_fp8_f32(c, d, r, true);
  return (uint32_t)r;
#else
  return f2e4m3_sw(a) | (f2e4m3_sw(b) << 8) | (f2e4m3_sw(c) << 16) | (f2e4m3_sw(d) << 24);
#endif
}
static __device__ __forceinline__ uint8_t f8_(float v) {
#if __has_builtin(__builtin_amdgcn_cvt_pk_fp8_f32)
  return (uint8_t)(__builtin_amdgcn_cvt_pk_fp8_f32(v, 0.f, 0, false) & 0xFF);
#else
  return (uint8_t)f2e4m3_sw(v);
#endif
}
static __device__ __forceinline__ long u2l(uint2 v) {
  union { uint2 v; long l; } x; x.v = v; return x.l;
}
// pinned 8B load (asm-produced -> non-rematerializable)
static __device__ __forceinline__ uint2 ldg_frag8(const uint2* p) {
  uint2 r;
  asm volatile("global_load_dwordx2 %0, %1, off" : "=v"(r) : "v"(p));
  return r;
}
static __device__ __forceinline__ void frag_fence() {
  asm volatile("s_waitcnt vmcnt(0)" ::: "memory");
  __builtin_amdgcn_sched_barrier(0);
}

// ---------------------------------------------------------------------------
// Kernel 0: weight prep + point math.
// f16 A-frag (16x16x32): lane l holds A[row=l&15][k=(l>>4)*8+j], j=0..7.
// PLAIN tiling: g = gt*16 + (l&15); k = kt*32 + ((l>>4)&3)*8 + ...
// fp8 frags use the same map with 8 fp8 bytes (2 VGPRs).
// ---------------------------------------------------------------------------
__global__ __launch_bounds__(256) void prep_kernel(
    const float* Wih_e, const float* Whh_e,
    const float* bih_e, const float* bhh_e,
    const float* Wih_d, const float* Whh_d,
    const float* bih_d, const float* bhh_d,
    const float* w1, const float* w2, const float* W1,
    const float* mask_point, float* out_gt, int* flat,
    char* ws, int w1_order) {
  uint32_t* pWih_e = (uint32_t*)(ws + OFF_PWIH_E);
  float*    bias_e = (float*)(ws + OFF_BIAS_E);
  float*    bias_d = (float*)(ws + OFF_BIAS_D);
  uint32_t* w1p    = (uint32_t*)(ws + OFF_W1P);
  uint32_t* w2p    = (uint32_t*)(ws + OFF_W2P);
  uint32_t* W1h    = (uint32_t*)(ws + OFF_W1H);

  int idx = blockIdx.x * 256 + threadIdx.x;
  if (idx < 32*512) {                             // pWih_e [k2][g] (for gx)
    int k2 = idx >> 9, g = idx & 511;
    pWih_e[idx] = packh(Wih_e[g*64 + 2*k2], Wih_e[g*64 + 2*k2 + 1]);
    return;
  }
  idx -= 32*512;
  if (idx < 512) { bias_e[idx] = bih_e[idx] + bhh_e[idx]; return; }
  idx -= 512;
  if (idx < 512) { bias_d[idx] = bih_d[idx] + bhh_d[idx]; return; }
  idx -= 512;
  if (idx < 288*64) {                             // conv w1 pairs [i2][c]
    int i2 = idx >> 6, c = idx & 63;
    if (w1_order) {
      int tap = i2 >> 5, cin = (i2 & 31) * 2;     // i2 = tap*32 + c2
      w1p[idx] = packh(w1[c*576 + cin*9 + tap], w1[c*576 + (cin+1)*9 + tap]);
    } else {
      w1p[idx] = packh(w1[c*576 + 2*i2], w1[c*576 + 2*i2 + 1]);
    }
    return;
  }
  idx -= 288*64;
  if (idx < 32*64) {                              // conv w2 pairs [c2][d]
    int c2 = idx >> 6, d = idx & 63;
    w2p[idx] = packh(w2[d*64 + 2*c2], w2[d*64 + 2*c2 + 1]);
    return;
  }
  idx -= 32*64;
  if (idx < 64*64) {                              // head W1 pairs [k2][j]
    int k2 = idx >> 6, j = idx & 63;
    W1h[idx] = packh(W1[j*128 + 2*k2], W1[j*128 + 2*k2 + 1]);
    return;
  }
  idx -= 64*64;
  if (idx < 32768) {                              // fehh f16 frags
    int j2 = idx & 3, lane = (idx >> 2) & 63, kt = (idx >> 8) & 3, gt = idx >> 10;
    int g = gt*16 + (lane & 15);
    int k = kt*32 + ((lane >> 4) & 3)*8 + 2*j2;
    ((uint32_t*)(ws + OFF_FEHH))[idx] = packh(Whh_e[g*128 + k], Whh_e[g*128 + k + 1]);
    return;
  }
  idx -= 32768;
  if (idx < 16384) {                              // fdih8 fp8 frags
    int half = idx & 1, lane = (idx >> 1) & 63, kt = (idx >> 7) & 3, gt = idx >> 9;
    int g = gt*16 + (lane & 15);
    int kb = kt*32 + ((lane >> 4) & 3)*8 + half*4;
    const float* W = Wih_d;
    ((uint32_t*)(ws + OFF_FDIH8))[(((gt*4 + kt)*64 + lane) << 1) | half] =
        pk4_fp8(W[g*128 + kb], W[g*128 + kb + 1], W[g*128 + kb + 2], W[g*128 + kb + 3]);
    return;
  }
  idx -= 16384;
  if (idx < 16384) {                              // fdhh8 fp8 frags
    int half = idx & 1, lane = (idx >> 1) & 63, kt = (idx >> 7) & 3, gt = idx >> 9;
    int g = gt*16 + (lane & 15);
    int kb = kt*32 + ((lane >> 4) & 3)*8 + half*4;
    const float* W = Whh_d;
    ((uint32_t*)(ws + OFF_FDHH8))[(((gt*4 + kt)*64 + lane) << 1) | half] =
        pk4_fp8(W[g*128 + kb], W[g*128 + kb + 1], W[g*128 + kb + 2], W[g*128 + kb + 3]);
    return;
  }
  idx -= 16384;
  if (idx < 16384) {                              // point math -> gt + flat
    float mx = mask_point[idx*2 + 0];
    float my = mask_point[idx*2 + 1];
    float fx = fminf(mx * 0.25f, 127.0f);
    float fy = fminf(my * 0.25f, 127.0f);
    out_gt[idx*2 + 0] = fx * 4.0f;
    out_gt[idx*2 + 1] = fy * 4.0f;
    flat[idx] = (int)(__fmaf_rn(fy, 128.0f, fx)); // fy*128 exact
    return;
  }
}
#define PREP_TOTAL (32*512 + 512 + 512 + 288*64 + 32*64 + 64*64 + 32768 + 16384 + 16384 + 16384)

// ---------------------------------------------------------------------------
// Kernel T: x [16][64][128][128] f32 -> xT [16][128][128][64] f16 (NHWC)
// ---------------------------------------------------------------------------
__global__ __launch_bounds__(256, 2) void transpose_kernel(
    const float* x, uint32_t* xT32) {
  __shared__ float lds[64][257];
  int bid = blockIdx.x;           // 1024 = 16 b x 16 yt x 4 xt
  int xt = bid & 3, yt = (bid >> 2) & 15, b = bid >> 6;
  int x0 = xt * 32, y0 = yt * 8;
  int tx = threadIdx.x & 31, ty = threadIdx.x >> 5;
  #pragma unroll 8
  for (int c = 0; c < 64; ++c)
    lds[c][ty*32 + tx] = x[((b*64 + c)*128 + (y0 + ty))*128 + (x0 + tx)];
  __syncthreads();
  #pragma unroll 8
  for (int r = 0; r < 32; ++r) {
    int i = threadIdx.x + 256*r;    // i = pos*32 + c2
    int c2 = i & 31, pos = i >> 5;
    int yy = pos >> 5, xx = pos & 31;
    float lo = lds[2*c2][yy*32 + xx], hi = lds[2*c2 + 1][yy*32 + xx];
    xT32[((b*128 + y0 + yy)*128 + (x0 + xx))*32 + c2] = packh(lo, hi);
  }
}

// ---------------------------------------------------------------------------
// Kernel 2: fused gathered conv (3x3 -> ReLU -> 1x1) at points, 4 pts/group
// ---------------------------------------------------------------------------
template <int MODE>
__global__ __launch_bounds__(256, 2) void conv_gather_kernel(
    const float* x, const uint32_t* xT32, const int* point_mask,
    const float* conv1_b, const float* conv2_b,
    const char* ws_ro, _Float16* dots_h, const int* flat) {
  __shared__ uint32_t w1s[64*292];    // 74752 B
  __shared__ uint32_t patch2[4*288];  //  4608 B
  __shared__ uint32_t tl2[4*32];      //   512 B

  const uint32_t* w1p = (const uint32_t*)(ws_ro + OFF_W1P);
  const uint32_t* w2p = (const uint32_t*)(ws_ro + OFF_W2P);
  int tid = threadIdx.x;
  for (int i = tid; i < 288*64; i += 256) {
    int i2 = i >> 6, cc = i & 63;
    w1s[cc*292 + i2] = w1p[i];
  }

  int q = tid >> 6, c = tid & 63;
  float c1b = conv1_b[c], c2b = conv2_b[c];

  for (int g = 0; g < 8; ++g) {
    int p0 = blockIdx.x * 32 + g * 4;
    __syncthreads();
    if (MODE == 1) {
      #pragma unroll
      for (int r = 0; r < 5; ++r) {  // 1152 u32 = 4 pts x 288
        int u = tid + 256*r;
        if (u < 1152) {
          int slot = u / 288, w = u - slot*288;
          int tap = w >> 5, c2i = w & 31;
          int p = p0 + slot;
          int fl = flat[p];
          int hh = fl >> 7, ww = fl & 127;
          int b = p >> 10;
          int dy = tap / 3, dx = tap - dy*3;
          int yy = hh + dy - 1, xx = ww + dx - 1;
          uint32_t v = 0u;
          if (yy >= 0 && yy < 128 && xx >= 0 && xx < 128)
            v = xT32[((b*128 + yy)*128 + xx)*32 + c2i];
          patch2[slot*288 + w] = v;
        }
      }
    } else {
      #pragma unroll
      for (int r = 0; r < 9; ++r) {  // 2304 halves = 4 pts x 576
        int l = tid + 256*r;
        int slot = l / 576;
        int within = l - slot*576;
        int cp = within / 9;
        int tap = within - cp*9;
        int p = p0 + slot;
        int fl = flat[p];
        int hh = fl >> 7, ww = fl & 127;
        int b = p >> 10;
        int yy = hh + tap/3 - 1, xx = ww + tap%3 - 1;
        float v = 0.0f;
        if (yy >= 0 && yy < 128 && xx >= 0 && xx < 128)
          v = x[((b*64 + cp)*128 + yy)*128 + xx];
        ((_Float16*)patch2)[l] = (_Float16)v;
      }
    }
    __syncthreads();

    float a0 = c1b, a1 = 0.f, a2 = 0.f, a3 = 0.f;
    int cbase = c * 292, pbase = q * 288;
    #pragma unroll 4
    for (int i2 = 0; i2 < 288; i2 += 4) {
      a0 = fdot2_(w1s[cbase + i2+0], patch2[pbase + i2+0], a0);
      a1 = fdot2_(w1s[cbase + i2+1], patch2[pbase + i2+1], a1);
      a2 = fdot2_(w1s[cbase + i2+2], patch2[pbase + i2+2], a2);
      a3 = fdot2_(w1s[cbase + i2+3], patch2[pbase + i2+3], a3);
    }
    float t1 = fmaxf((a0 + a1) + (a2 + a3), 0.0f);
    ((_Float16*)tl2)[q*64 + c] = (_Float16)t1;
    // tl2[q] written/read by same wave -> no barrier

    float acc2 = c2b;
    #pragma unroll
    for (int c2i = 0; c2i < 32; ++c2i)
      acc2 = fdot2_(w2p[c2i*64 + c], tl2[q*32 + c2i], acc2);
    int p = p0 + q;
    acc2 *= (float)point_mask[p];
    int k = p & 31, bn = p >> 5;
    dots_h[(k*NSEQ + bn)*64 + c] = (_Float16)acc2;   // time-major [k][bn][d]
  }
}

// ---------------------------------------------------------------------------
// Kernel G: encoder x-projection GEMM: gx[bn][t][g] (SEQ-MAJOR for lstm LDS
// staging) = bias_e[g] + Wih_e . dots[t,bn]
// ---------------------------------------------------------------------------
__global__ __launch_bounds__(512, 2) void gx_gemm_kernel(
    const char* ws_ro, _Float16* gx) {
  const uint32_t* pWih_e = (const uint32_t*)(ws_ro + OFF_PWIH_E);
  const float*    bias_e = (const float*)(ws_ro + OFF_BIAS_E);
  const uint32_t* dots_u = (const uint32_t*)(ws_ro + OFF_DOTS);
  __shared__ uint32_t xs[32][32];   // 4 KB
  int tid = threadIdx.x;
  int R0 = blockIdx.x * 32;
  for (int i = tid; i < 32*32; i += 512)
    xs[i >> 5][i & 31] = dots_u[(R0 + (i >> 5))*32 + (i & 31)];
  uint32_t wv[32];
  #pragma unroll
  for (int k = 0; k < 32; ++k) wv[k] = pWih_e[k*512 + tid];
  float bs = bias_e[tid];
  __syncthreads();
  #pragma unroll 2
  for (int r = 0; r < 32; ++r) {
    float a = bs;
    #pragma unroll
    for (int k = 0; k < 32; ++k) a = fdot2_(wv[k], xs[r][k], a);
    int R = R0 + r;                    // R = t*512 + bn
    int t = R >> 9, bn = R & 511;
    gx[((size_t)bn*32 + t)*512 + tid] = (_Float16)a;   // seq-major
  }
}

// ---------------------------------------------------------------------------
// Kernel 3: recurrent LSTMs via MFMA (gb-roundtrip dedup nonlinearity) +
// fused MLP head. 256 blocks x 512 threads (8 waves); 2 seqs/block.
// Wave w owns gate-tiles gt = 4w..4w+3.
// Encoder: f16 MFMA; gx staged ONCE into LDS (64 KB, coalesced) -> per-step
// gx access is LDS, removing the exposed L3 round-trip from the serial chain.
// Decoder: fp8 MFMA (32 asm-pinned frags); h as fp8 bytes in LDS.
// ---------------------------------------------------------------------------
__global__ __launch_bounds__(512, 2) void lstm_head_kernel(
    const char* ws_ro, const _Float16* gx,
    const float* b1, const float* W2, const float* b2,
    float* out_kp) {
  const f16x8* fehh   = (const f16x8*)(ws_ro + OFF_FEHH);
  const uint2* fdih8  = (const uint2*)(ws_ro + OFF_FDIH8);
  const uint2* fdhh8  = (const uint2*)(ws_ro + OFF_FDHH8);
  const float* bias_d = (const float*)(ws_ro + OFF_BIAS_D);
  const uint32_t* W1h = (const uint32_t*)(ws_ro + OFF_W1H);

  __shared__ __attribute__((aligned(16))) uint32_t gxs[2][32][256];   // 64 KB f16
  __shared__ __attribute__((aligned(16))) uint32_t enc8[2][32][32];   //  8 KB fp8
  __shared__ __attribute__((aligned(16))) uint32_t dech2[2][32][64];  // 16 KB f16
  __shared__ __attribute__((aligned(16))) uint32_t hb2[2][64];        // 512 B f16
  __shared__ __attribute__((aligned(16))) uint32_t hb8[2][32];        // 256 B fp8
  __shared__ __attribute__((aligned(16))) float    gb[2][512];        //  4 KB
  __shared__ float hidf[64][65];                                      // 16.6 KB

  int tid  = threadIdx.x;
  int lane = tid & 63, wave = tid >> 6;
  int col  = lane & 15, lgrp = lane >> 4;
  int bn0  = blockIdx.x * 2;

  int s_nl = tid >> 7, u_nl = tid & 127;    // nonlinearity role (tid < 256)
  float c_reg = 0.0f;

  // ---- stage gx for both seqs: 2 x 32 x 512 f16 = 64 KB, contiguous ----
  {
    const uint32_t* gxu = (const uint32_t*)(gx + (size_t)bn0*32*512);
    for (int i = tid; i < 8192; i += 512)
      ((uint32_t*)gxs)[i] = gxu[i];
  }

  // encoder h-weights as f16 MFMA fragments (16 frags)
  f16x8 ae[4][4];
  #pragma unroll
  for (int g0 = 0; g0 < 4; ++g0)
    #pragma unroll
    for (int kt = 0; kt < 4; ++kt)
      ae[g0][kt] = fehh[((wave*4 + g0)*4 + kt)*64 + lane];

  if (tid < 128) hb2[tid >> 6][tid & 63] = 0u;
  __syncthreads();

  const f16x8 bzero = {};

  // ----------------- encoder -----------------
  for (int t = 0; t < 32; ++t) {
    f16x8 bf[4];
    #pragma unroll
    for (int kt = 0; kt < 4; ++kt) {
      if (col < 2) bf[kt] = *(const f16x8*)&hb2[col][kt*16 + lgrp*4];
      else         bf[kt] = bzero;
    }
    #pragma unroll
    for (int g0 = 0; g0 < 4; ++g0) {
      f32x4 acc = {0.f, 0.f, 0.f, 0.f};
      #pragma unroll
      for (int kt = 0; kt < 4; ++kt)
        acc = __builtin_amdgcn_mfma_f32_16x16x32_f16(ae[g0][kt], bf[kt], acc, 0, 0, 0);
      if (col < 2)
        *(f32x4*)&gb[col][(wave*4 + g0)*16 + lgrp*4] = acc;
    }
    __syncthreads();
    if (tid < 256) {
      const _Float16* gr = (const _Float16*)&gxs[s_nl][t][0];
      float ig = sig_ (gb[s_nl][u_nl]       + (float)gr[u_nl]);
      float fg = sig_ (gb[s_nl][128 + u_nl] + (float)gr[128 + u_nl]);
      float gg = tanh_(gb[s_nl][256 + u_nl] + (float)gr[256 + u_nl]);
      float og = sig_ (gb[s_nl][384 + u_nl] + (float)gr[384 + u_nl]);
      c_reg = fg * c_reg + ig * gg;
      float hh = og * tanh_(c_reg);
      ((_Float16*)&hb2[s_nl][0])[u_nl] = (_Float16)hh;  // enc recurrence (f16)
      ((uint8_t*)&enc8[s_nl][t][0])[u_nl] = f8_(hh);    // dec consumption (fp8)
    }
    __syncthreads();
  }

  // ---- transition: dec recurrent h (fp8) = enc final h ----
  if (tid < 256) {
    float hv = (float)((_Float16*)&hb2[s_nl][0])[u_nl];
    ((uint8_t*)&hb8[s_nl][0])[u_nl] = f8_(hv);
  }

  // ---- decoder weights: 32 asm-pinned fp8 frags (64 VGPR) ----
  uint2 dih8[4][4], dhh8[4][4];
  #pragma unroll
  for (int g0 = 0; g0 < 4; ++g0)
    #pragma unroll
    for (int kt = 0; kt < 4; ++kt) {
      dih8[g0][kt] = ldg_frag8(&fdih8[((wave*4 + g0)*4 + kt)*64 + lane]);
      dhh8[g0][kt] = ldg_frag8(&fdhh8[((wave*4 + g0)*4 + kt)*64 + lane]);
    }
  frag_fence();
  float bdi = 0.f, bdf = 0.f, bdg = 0.f, bdo = 0.f;
  if (tid < 256) {
    bdi = bias_d[u_nl];       bdf = bias_d[128 + u_nl];
    bdg = bias_d[256 + u_nl]; bdo = bias_d[384 + u_nl];
  }
  __syncthreads();

  // ----------------- decoder (fp8 MFMA) -----------------
  for (int t = 0; t < 32; ++t) {
    long bx[4], bh[4];
    #pragma unroll
    for (int kt = 0; kt < 4; ++kt) {
      if (col < 2) {
        bx[kt] = u2l(*(const uint2*)&enc8[col][t][kt*8 + lgrp*2]);
        bh[kt] = u2l(*(const uint2*)&hb8[col][kt*8 + lgrp*2]);
      } else { bx[kt] = 0; bh[kt] = 0; }
    }
    #pragma unroll
    for (int g0 = 0; g0 < 4; ++g0) {
      f32x4 acc = {0.f, 0.f, 0.f, 0.f};
      #pragma unroll
      for (int kt = 0; kt < 4; ++kt)
        acc = __builtin_amdgcn_mfma_f32_16x16x32_fp8_fp8(
            u2l(dih8[g0][kt]), bx[kt], acc, 0, 0, 0);
      #pragma unroll
      for (int kt = 0; kt < 4; ++kt)
        acc = __builtin_amdgcn_mfma_f32_16x16x32_fp8_fp8(
            u2l(dhh8[g0][kt]), bh[kt], acc, 0, 0, 0);
      if (col < 2)
        *(f32x4*)&gb[col][(wave*4 + g0)*16 + lgrp*4] = acc;
    }
    __syncthreads();
    if (tid < 256) {
      float ig = sig_ (gb[s_nl][u_nl]       + bdi);
      float fg = sig_ (gb[s_nl][128 + u_nl] + bdf);
      float gg = tanh_(gb[s_nl][256 + u_nl] + bdg);
      float og = sig_ (gb[s_nl][384 + u_nl] + bdo);
      c_reg = fg * c_reg + ig * gg;
      float hh = og * tanh_(c_reg);
      ((uint8_t*)&hb8[s_nl][0])[u_nl] = f8_(hh);            // dec recurrence
      ((_Float16*)&dech2[s_nl][t][0])[u_nl] = (_Float16)hh; // head input (f16)
    }
    __syncthreads();
  }

  // ----------------- fused head: relu(dec@W1.T+b1)@W2.T+b2 ----------------
  {
    int j = tid & 63, w = tid >> 6;       // 8 waves; rows st = w + 8*m
    float acc[8];
    #pragma unroll
    for (int m = 0; m < 8; ++m) acc[m] = b1[j];
    #pragma unroll 8
    for (int k = 0; k < 64; ++k) {
      uint32_t wv = W1h[k*64 + j];
      #pragma unroll
      for (int m = 0; m < 8; ++m) {
        int st = w + 8*m;
        acc[m] = fdot2_(wv, dech2[st >> 5][st & 31][k], acc[m]);
      }
    }
    #pragma unroll
    for (int m = 0; m < 8; ++m) {
      int st = w + 8*m;
      hidf[st][j] = fmaxf(acc[m], 0.0f);
    }
  }
  __syncthreads();
  if (tid < 128) {
    int st = tid >> 1, e = tid & 1;
    float acc = b2[e];
    #pragma unroll 16
    for (int j = 0; j < 64; ++j) acc += W2[e*64 + j] * hidf[st][j];
    int s = st >> 5, t = st & 31;
    out_kp[((bn0 + s)*32 + t)*2 + e] = acc;
  }
}

// ---------------------------------------------------------------------------
// Launch
// ---------------------------------------------------------------------------
extern "C" void kernel_launch(void* const* d_in, const int* in_sizes, int n_in,
                              void* d_out, int out_size, void* d_ws, size_t ws_size,
                              hipStream_t stream) {
  const float* x          = (const float*)d_in[0];
  const float* mask_point = (const float*)d_in[1];
  const int*   point_mask = (const int*)d_in[2];
  const float* conv1_w    = (const float*)d_in[3];
  const float* conv1_b    = (const float*)d_in[4];
  const float* conv2_w    = (const float*)d_in[5];
  const float* conv2_b    = (const float*)d_in[6];
  const float* Wih_e      = (const float*)d_in[7];
  const float* Whh_e      = (const float*)d_in[8];
  const float* bih_e      = (const float*)d_in[9];
  const float* bhh_e      = (const float*)d_in[10];
  const float* Wih_d      = (const float*)d_in[11];
  const float* Whh_d      = (const float*)d_in[12];
  const float* bih_d      = (const float*)d_in[13];
  const float* bhh_d      = (const float*)d_in[14];
  const float* W1         = (const float*)d_in[15];
  const float* b1         = (const float*)d_in[16];
  const float* W2         = (const float*)d_in[17];
  const float* b2         = (const float*)d_in[18];

  float* out = (float*)d_out;
  char*  ws  = (char*)d_ws;

  const bool use_xt = (ws_size >= WS_NEED_XT);
  // gx overlays the xT region (dead after conv_gather); fallback otherwise
  _Float16* gx = (_Float16*)(ws + (use_xt ? OFF_XT : OFF_GX_FB));

  prep_kernel<<<(PREP_TOTAL + 255)/256, 256, 0, stream>>>(
      Wih_e, Whh_e, bih_e, bhh_e, Wih_d, Whh_d, bih_d, bhh_d,
      conv1_w, conv2_w, W1, mask_point, out + 32768, (int*)(ws + OFF_FLAT),
      ws, use_xt ? 1 : 0);

  if (use_xt) {
    transpose_kernel<<<1024, 256, 0, stream>>>(x, (uint32_t*)(ws + OFF_XT));
    conv_gather_kernel<1><<<512, 256, 0, stream>>>(
        x, (const uint32_t*)(ws + OFF_XT), point_mask, conv1_b, conv2_b,
        ws, (_Float16*)(ws + OFF_DOTS), (const int*)(ws + OFF_FLAT));
  } else {
    conv_gather_kernel<0><<<512, 256, 0, stream>>>(
        x, nullptr, point_mask, conv1_b, conv2_b,
        ws, (_Float16*)(ws + OFF_DOTS), (const int*)(ws + OFF_FLAT));
  }

  gx_gemm_kernel<<<512, 512, 0, stream>>>(ws, gx);

  lstm_head_kernel<<<256, 512, 0, stream>>>(ws, gx, b1, W2, b2, out);
}

// Round 14
// 136.491 us; speedup vs baseline: 1.2371x; 1.1705x over previous
//
#include <hip/hip_runtime.h>
#include <stdint.h>

// ---------------------------------------------------------------------------
// Problem constants
// ---------------------------------------------------------------------------
#define NSEQ 512        // B*N
#define HIDN 128

// ws byte offsets
#define OFF_PWIH_E 0                            // 32*512*4 = 65536 (gx weights)
#define OFF_BIAS_E 65536                        // 512 f32
#define OFF_BIAS_D 67584                        // 512 f32
#define OFF_W1P    69632                        // conv w1 f16 pairs [288][64]
#define OFF_W2P    143360                       // conv w2 f16 pairs [32][64]
#define OFF_FLAT   151552                       // [16384] int
#define OFF_W1H    217088                       // head W1 f16 pairs [64][64]
#define OFF_FEHH   233472                       // enc Whh f16 frags, 128 KB
#define OFF_FDIH8  364544                       // dec Wih fp8 frags, 64 KB
#define OFF_FDHH8  430080                       // dec Whh fp8 frags, 64 KB
#define OFF_W2T    495616                       // conv w2 frags [64][36] u32 = 9216 B
#define OFF_DOTS   (1024*1024)                  // [32][512][64] f16 = 2 MB
#define OFF_GX_FB  (3*1024*1024)                // fallback gx area
#define OFF_XT     (4*1024*1024)                // xT f16 = 33.5 MB (gx overlays)
#define WS_NEED_XT ((size_t)(4*1024*1024) + (size_t)16*128*128*64*2 + 1024)

typedef _Float16 h2f __attribute__((ext_vector_type(2)));
typedef _Float16 f16x8 __attribute__((ext_vector_type(8)));
typedef float    f32x4 __attribute__((ext_vector_type(4)));

static __device__ __forceinline__ h2f u2h(uint32_t u) {
  union { uint32_t u; h2f h; } v; v.u = u; return v.h;
}

#if __has_builtin(__builtin_amdgcn_fdot2)
static __device__ __forceinline__ float fdot2_(uint32_t a, uint32_t b, float c) {
  return __builtin_amdgcn_fdot2(u2h(a), u2h(b), c, false);
}
#else
static __device__ __forceinline__ float fdot2_(uint32_t a, uint32_t b, float c) {
  h2f x = u2h(a), y = u2h(b);
  return c + (float)x.x * (float)y.x + (float)x.y * (float)y.y;
}
#endif

static __device__ __forceinline__ uint32_t packh(float a, float b) {
  union { _Float16 h[2]; uint32_t u; } v;
  v.h[0] = (_Float16)a; v.h[1] = (_Float16)b; return v.u;
}
static __device__ __forceinline__ float sig_(float x) {
  return 1.0f / (1.0f + __expf(-x));
}
static __device__ __forceinline__ float tanh_(float x) {
  return 1.0f - 2.0f / (1.0f + __expf(2.0f * x));
}

// ---- fp8 e4m3fn helpers ----------------------------------------------------
static __device__ __forceinline__ uint32_t f2e4m3_sw(float f) {
  union { float f; uint32_t u; } v; v.f = f;
  uint32_t s = (v.u >> 24) & 0x80u;
  float af = fabsf(f);
  if (af == 0.0f) return s;
  if (af >= 448.0f) return s | 0x7Eu;
  int e; float m = frexpf(af, &e);      // af = m*2^e, m in [0.5,1)
  int E = e + 6;                         // 1.xxx*2^(e-1), bias 7
  float mant = m * 2.0f - 1.0f;
  int mm = (int)(mant * 8.0f + 0.5f);
  if (mm == 8) { mm = 0; ++E; }
  if (E < 1) {                           // subnormal: step 2^-9
    int sm = (int)(af * 512.0f + 0.5f);
    return s | (uint32_t)(sm > 7 ? 7 : sm);
  }
  if (E > 15) return s | 0x7Eu;
  return s | ((uint32_t)E << 3) | (uint32_t)mm;
}
static __device__ __forceinline__ uint32_t pk4_fp8(float a, float b, float c, float d) {
#if __has_builtin(__builtin_amdgcn_cvt_pk_fp8_f32)
  int r = __builtin_amdgcn_cvt_pk_fp8_f32(a, b, 0, false);
  r = __builtin_amdgcn_cvt_pk_fp8_f32(c, d, r, true);
  return (uint32_t)r;
#else
  return f2e4m3_sw(a) | (f2e4m3_sw(b) << 8) | (f2e4m3_sw(c) << 16) | (f2e4m3_sw(d) << 24);
#endif
}
static __device__ __forceinline__ uint8_t f8_(float v) {
#if __has_builtin(__builtin_amdgcn_cvt_pk_fp8_f32)
  return (uint8_t)(__builtin_amdgcn_cvt_pk_fp8_f32(v, 0.f, 0, false) & 0xFF);
#else
  return (uint8_t)f2e4m3_sw(v);
#endif
}
static __device__ __forceinline__ long u2l(uint2 v) {
  union { uint2 v; long l; } x; x.v = v; return x.l;
}
// pinned 8B load (asm-produced -> non-rematerializable)
static __device__ __forceinline__ uint2 ldg_frag8(const uint2* p) {
  uint2 r;
  asm volatile("global_load_dwordx2 %0, %1, off" : "=v"(r) : "v"(p));
  return r;
}
static __device__ __forceinline__ void frag_fence() {
  asm volatile("s_waitcnt vmcnt(0)" ::: "memory");
  __builtin_amdgcn_sched_barrier(0);
}

// ---------------------------------------------------------------------------
// Kernel 0: weight prep + point math.
// f16 A-frag (16x16x32): lane l holds A[row=l&15][k=(l>>4)*8+j], j=0..7.
// PLAIN tiling: g = gt*16 + (l&15); k = kt*32 + ((l>>4)&3)*8 + ...
// fp8 frags use the same map with 8 fp8 bytes (2 VGPRs).
// ---------------------------------------------------------------------------
__global__ __launch_bounds__(256) void prep_kernel(
    const float* Wih_e, const float* Whh_e,
    const float* bih_e, const float* bhh_e,
    const float* Wih_d, const float* Whh_d,
    const float* bih_d, const float* bhh_d,
    const float* w1, const float* w2, const float* W1,
    const float* mask_point, float* out_gt, int* flat,
    char* ws, int w1_order) {
  uint32_t* pWih_e = (uint32_t*)(ws + OFF_PWIH_E);
  float*    bias_e = (float*)(ws + OFF_BIAS_E);
  float*    bias_d = (float*)(ws + OFF_BIAS_D);
  uint32_t* w1p    = (uint32_t*)(ws + OFF_W1P);
  uint32_t* w2p    = (uint32_t*)(ws + OFF_W2P);
  uint32_t* W1h    = (uint32_t*)(ws + OFF_W1H);
  uint32_t* w2t    = (uint32_t*)(ws + OFF_W2T);

  int idx = blockIdx.x * 256 + threadIdx.x;
  if (idx < 32*512) {                             // pWih_e [k2][g] (for gx)
    int k2 = idx >> 9, g = idx & 511;
    pWih_e[idx] = packh(Wih_e[g*64 + 2*k2], Wih_e[g*64 + 2*k2 + 1]);
    return;
  }
  idx -= 32*512;
  if (idx < 512) { bias_e[idx] = bih_e[idx] + bhh_e[idx]; return; }
  idx -= 512;
  if (idx < 512) { bias_d[idx] = bih_d[idx] + bhh_d[idx]; return; }
  idx -= 512;
  if (idx < 288*64) {                             // conv w1 pairs [i2][c]
    int i2 = idx >> 6, c = idx & 63;
    if (w1_order) {
      int tap = i2 >> 5, cin = (i2 & 31) * 2;     // i2 = tap*32 + c2
      w1p[idx] = packh(w1[c*576 + cin*9 + tap], w1[c*576 + (cin+1)*9 + tap]);
    } else {
      w1p[idx] = packh(w1[c*576 + 2*i2], w1[c*576 + 2*i2 + 1]);
    }
    return;
  }
  idx -= 288*64;
  if (idx < 32*64) {                              // conv w2 pairs [c2][d]
    int c2 = idx >> 6, d = idx & 63;
    w2p[idx] = packh(w2[d*64 + 2*c2], w2[d*64 + 2*c2 + 1]);
    return;
  }
  idx -= 32*64;
  if (idx < 64*64) {                              // head W1 pairs [k2][j]
    int k2 = idx >> 6, j = idx & 63;
    W1h[idx] = packh(W1[j*128 + 2*k2], W1[j*128 + 2*k2 + 1]);
    return;
  }
  idx -= 64*64;
  if (idx < 32768) {                              // fehh f16 frags
    int j2 = idx & 3, lane = (idx >> 2) & 63, kt = (idx >> 8) & 3, gt = idx >> 10;
    int g = gt*16 + (lane & 15);
    int k = kt*32 + ((lane >> 4) & 3)*8 + 2*j2;
    ((uint32_t*)(ws + OFF_FEHH))[idx] = packh(Whh_e[g*128 + k], Whh_e[g*128 + k + 1]);
    return;
  }
  idx -= 32768;
  if (idx < 16384) {                              // fdih8 fp8 frags
    int half = idx & 1, lane = (idx >> 1) & 63, kt = (idx >> 7) & 3, gt = idx >> 9;
    int g = gt*16 + (lane & 15);
    int kb = kt*32 + ((lane >> 4) & 3)*8 + half*4;
    const float* W = Wih_d;
    ((uint32_t*)(ws + OFF_FDIH8))[(((gt*4 + kt)*64 + lane) << 1) | half] =
        pk4_fp8(W[g*128 + kb], W[g*128 + kb + 1], W[g*128 + kb + 2], W[g*128 + kb + 3]);
    return;
  }
  idx -= 16384;
  if (idx < 16384) {                              // fdhh8 fp8 frags
    int half = idx & 1, lane = (idx >> 1) & 63, kt = (idx >> 7) & 3, gt = idx >> 9;
    int g = gt*16 + (lane & 15);
    int kb = kt*32 + ((lane >> 4) & 3)*8 + half*4;
    const float* W = Whh_d;
    ((uint32_t*)(ws + OFF_FDHH8))[(((gt*4 + kt)*64 + lane) << 1) | half] =
        pk4_fp8(W[g*128 + kb], W[g*128 + kb + 1], W[g*128 + kb + 2], W[g*128 + kb + 3]);
    return;
  }
  idx -= 16384;
  if (idx < 64*36) {                              // w2t [d][c2] pad 36 (MFMA A)
    int d = idx / 36, c2 = idx - (idx/36)*36;
    w2t[idx] = (c2 < 32) ? packh(w2[d*64 + 2*c2], w2[d*64 + 2*c2 + 1]) : 0u;
    return;
  }
  idx -= 64*36;
  if (idx < 16384) {                              // point math -> gt + flat
    float mx = mask_point[idx*2 + 0];
    float my = mask_point[idx*2 + 1];
    float fx = fminf(mx * 0.25f, 127.0f);
    float fy = fminf(my * 0.25f, 127.0f);
    out_gt[idx*2 + 0] = fx * 4.0f;
    out_gt[idx*2 + 1] = fy * 4.0f;
    flat[idx] = (int)(__fmaf_rn(fy, 128.0f, fx)); // fy*128 exact
    return;
  }
}
#define PREP_TOTAL (32*512 + 512 + 512 + 288*64 + 32*64 + 64*64 + 32768 + 16384 + 16384 + 64*36 + 16384)

// ---------------------------------------------------------------------------
// Kernel T: x [16][64][128][128] f32 -> xT [16][128][128][64] f16 (NHWC)
// ---------------------------------------------------------------------------
__global__ __launch_bounds__(256, 2) void transpose_kernel(
    const float* x, uint32_t* xT32) {
  __shared__ float lds[64][257];
  int bid = blockIdx.x;           // 1024 = 16 b x 16 yt x 4 xt
  int xt = bid & 3, yt = (bid >> 2) & 15, b = bid >> 6;
  int x0 = xt * 32, y0 = yt * 8;
  int tx = threadIdx.x & 31, ty = threadIdx.x >> 5;
  #pragma unroll 8
  for (int c = 0; c < 64; ++c)
    lds[c][ty*32 + tx] = x[((b*64 + c)*128 + (y0 + ty))*128 + (x0 + tx)];
  __syncthreads();
  #pragma unroll 8
  for (int r = 0; r < 32; ++r) {
    int i = threadIdx.x + 256*r;    // i = pos*32 + c2
    int c2 = i & 31, pos = i >> 5;
    int yy = pos >> 5, xx = pos & 31;
    float lo = lds[2*c2][yy*32 + xx], hi = lds[2*c2 + 1][yy*32 + xx];
    xT32[((b*128 + y0 + yy)*128 + (x0 + xx))*32 + c2] = packh(lo, hi);
  }
}

// ---------------------------------------------------------------------------
// Kernel 2 (MFMA): gathered conv (3x3 -> ReLU -> 1x1) at points.
// 256 blocks x 512 threads (8 waves); 64 points/block in 2 iters of 32.
// conv1 = [64ch x 576] . [576 x 32pts]: wave (r,g) owns out tile
// [r*16 ch) x [g*16 pts), 18 k-tiles of mfma_f32_16x16x32_f16.
// conv2 = 2 more k-tiles (W2 frags in registers from w2t).
// LDS: w1s [c][292] (2-way), patch2 [32][292] (2-way), t1 [32][36].
// ---------------------------------------------------------------------------
__global__ __launch_bounds__(512, 1) void conv_mfma_kernel(
    const uint32_t* xT32, const int* point_mask,
    const float* conv1_b, const float* conv2_b,
    const char* ws_ro, _Float16* dots_h, const int* flat) {
  __shared__ __attribute__((aligned(16))) uint32_t w1s[64*292];    // 74752 B
  __shared__ __attribute__((aligned(16))) uint32_t patch2[32*292]; // 37376 B
  __shared__ __attribute__((aligned(16))) uint32_t t1s[32*36];     //  4608 B

  const uint32_t* w1p = (const uint32_t*)(ws_ro + OFF_W1P);
  const uint32_t* w2t = (const uint32_t*)(ws_ro + OFF_W2T);
  int tid  = threadIdx.x;
  int lane = tid & 63, wave = tid >> 6;
  int r = wave & 3, g = wave >> 2;      // row-tile (channels), point-group
  int cl = lane & 15, lgrp = lane >> 4;

  for (int i = tid; i < 288*64; i += 512) {
    int i2 = i >> 6, cc = i & 63;
    w1s[cc*292 + i2] = w1p[i];
  }

  // conv2 A-frags (held in registers; rows d = r*16+cl)
  uint4 a2[2];
  #pragma unroll
  for (int kt = 0; kt < 2; ++kt)
    a2[kt] = *(const uint4*)&w2t[(r*16 + cl)*36 + kt*16 + lgrp*4];

  float4 b1v = *(const float4*)&conv1_b[r*16 + lgrp*4];
  float4 b2v = *(const float4*)&conv2_b[r*16 + lgrp*4];

  for (int it = 0; it < 2; ++it) {
    int p0 = blockIdx.x * 64 + it * 32;
    __syncthreads();                    // patch2/t1s reuse (+ w1s ready, it=0)
    #pragma unroll
    for (int rr = 0; rr < 18; ++rr) {   // 9216 u32 = 32 slots x 288
      int u = tid + 512*rr;
      int slot = u / 288, w = u - slot*288;
      int tap = w >> 5, c2i = w & 31;
      int p = p0 + slot;
      int fl = flat[p];
      int hh = fl >> 7, ww = fl & 127;
      int b = p >> 10;
      int dy = tap / 3, dx = tap - dy*3;
      int yy = hh + dy - 1, xx = ww + dx - 1;
      uint32_t v = 0u;
      if (yy >= 0 && yy < 128 && xx >= 0 && xx < 128)
        v = xT32[((b*128 + yy)*128 + xx)*32 + c2i];
      patch2[slot*292 + w] = v;
    }
    __syncthreads();

    // conv1 MFMA: 18 k-tiles
    f32x4 acc = {b1v.x, b1v.y, b1v.z, b1v.w};
    #pragma unroll
    for (int kt = 0; kt < 18; ++kt) {
      f16x8 af = *(const f16x8*)&w1s[(r*16 + cl)*292 + kt*16 + lgrp*4];
      f16x8 bf = *(const f16x8*)&patch2[(g*16 + cl)*292 + kt*16 + lgrp*4];
      acc = __builtin_amdgcn_mfma_f32_16x16x32_f16(af, bf, acc, 0, 0, 0);
    }
    // relu -> t1 (f16). lane: point = g*16+cl, channels c0..c0+3, c0=r*16+lgrp*4
    {
      int trow = (g*16 + cl)*36 + r*8 + lgrp*2;
      t1s[trow]     = packh(fmaxf(acc[0], 0.f), fmaxf(acc[1], 0.f));
      t1s[trow + 1] = packh(fmaxf(acc[2], 0.f), fmaxf(acc[3], 0.f));
    }
    __syncthreads();

    // conv2 MFMA: 2 k-tiles; rows d, cols points
    f32x4 acc2 = {b2v.x, b2v.y, b2v.z, b2v.w};
    #pragma unroll
    for (int kt = 0; kt < 2; ++kt) {
      f16x8 af; __builtin_memcpy(&af, &a2[kt], 16);
      f16x8 bf = *(const f16x8*)&t1s[(g*16 + cl)*36 + kt*16 + lgrp*4];
      acc2 = __builtin_amdgcn_mfma_f32_16x16x32_f16(af, bf, acc2, 0, 0, 0);
    }
    {
      int p = p0 + g*16 + cl;
      float m = (float)point_mask[p];
      int kk = p & 31, bn = p >> 5;
      int d0 = r*16 + lgrp*4;
      uint2 o;
      o.x = packh(acc2[0]*m, acc2[1]*m);
      o.y = packh(acc2[2]*m, acc2[3]*m);
      *(uint2*)&dots_h[(size_t)(kk*NSEQ + bn)*64 + d0] = o;
    }
  }
}

// ---------------------------------------------------------------------------
// Kernel 2 fallback (no xT): scalar gathered conv from NCHW f32.
// ---------------------------------------------------------------------------
__global__ __launch_bounds__(256, 2) void conv_gather_kernel(
    const float* x, const int* point_mask,
    const float* conv1_b, const float* conv2_b,
    const char* ws_ro, _Float16* dots_h, const int* flat) {
  __shared__ uint32_t w1s[64*292];
  __shared__ uint32_t patch2[4*288];
  __shared__ uint32_t tl2[4*32];

  const uint32_t* w1p = (const uint32_t*)(ws_ro + OFF_W1P);
  const uint32_t* w2p = (const uint32_t*)(ws_ro + OFF_W2P);
  int tid = threadIdx.x;
  for (int i = tid; i < 288*64; i += 256) {
    int i2 = i >> 6, cc = i & 63;
    w1s[cc*292 + i2] = w1p[i];
  }

  int q = tid >> 6, c = tid & 63;
  float c1b = conv1_b[c], c2b = conv2_b[c];

  for (int g = 0; g < 8; ++g) {
    int p0 = blockIdx.x * 32 + g * 4;
    __syncthreads();
    #pragma unroll
    for (int r = 0; r < 9; ++r) {
      int l = tid + 256*r;
      int slot = l / 576;
      int within = l - slot*576;
      int cp = within / 9;
      int tap = within - cp*9;
      int p = p0 + slot;
      int fl = flat[p];
      int hh = fl >> 7, ww = fl & 127;
      int b = p >> 10;
      int yy = hh + tap/3 - 1, xx = ww + tap%3 - 1;
      float v = 0.0f;
      if (yy >= 0 && yy < 128 && xx >= 0 && xx < 128)
        v = x[((b*64 + cp)*128 + yy)*128 + xx];
      ((_Float16*)patch2)[l] = (_Float16)v;
    }
    __syncthreads();

    float a0 = c1b, a1 = 0.f, a2 = 0.f, a3 = 0.f;
    int cbase = c * 292, pbase = q * 288;
    #pragma unroll 4
    for (int i2 = 0; i2 < 288; i2 += 4) {
      a0 = fdot2_(w1s[cbase + i2+0], patch2[pbase + i2+0], a0);
      a1 = fdot2_(w1s[cbase + i2+1], patch2[pbase + i2+1], a1);
      a2 = fdot2_(w1s[cbase + i2+2], patch2[pbase + i2+2], a2);
      a3 = fdot2_(w1s[cbase + i2+3], patch2[pbase + i2+3], a3);
    }
    float t1 = fmaxf((a0 + a1) + (a2 + a3), 0.0f);
    ((_Float16*)tl2)[q*64 + c] = (_Float16)t1;

    float acc2 = c2b;
    #pragma unroll
    for (int c2i = 0; c2i < 32; ++c2i)
      acc2 = fdot2_(w2p[c2i*64 + c], tl2[q*32 + c2i], acc2);
    int p = p0 + q;
    acc2 *= (float)point_mask[p];
    int k = p & 31, bn = p >> 5;
    dots_h[(k*NSEQ + bn)*64 + c] = (_Float16)acc2;
  }
}

// ---------------------------------------------------------------------------
// Kernel G: encoder x-projection GEMM: gx[bn][t][g] (seq-major)
// ---------------------------------------------------------------------------
__global__ __launch_bounds__(512, 2) void gx_gemm_kernel(
    const char* ws_ro, _Float16* gx) {
  const uint32_t* pWih_e = (const uint32_t*)(ws_ro + OFF_PWIH_E);
  const float*    bias_e = (const float*)(ws_ro + OFF_BIAS_E);
  const uint32_t* dots_u = (const uint32_t*)(ws_ro + OFF_DOTS);
  __shared__ uint32_t xs[32][32];
  int tid = threadIdx.x;
  int R0 = blockIdx.x * 32;
  for (int i = tid; i < 32*32; i += 512)
    xs[i >> 5][i & 31] = dots_u[(R0 + (i >> 5))*32 + (i & 31)];
  uint32_t wv[32];
  #pragma unroll
  for (int k = 0; k < 32; ++k) wv[k] = pWih_e[k*512 + tid];
  float bs = bias_e[tid];
  __syncthreads();
  #pragma unroll 2
  for (int r = 0; r < 32; ++r) {
    float a = bs;
    #pragma unroll
    for (int k = 0; k < 32; ++k) a = fdot2_(wv[k], xs[r][k], a);
    int R = R0 + r;                    // R = t*512 + bn
    int t = R >> 9, bn = R & 511;
    gx[((size_t)bn*32 + t)*512 + tid] = (_Float16)a;
  }
}

// ---------------------------------------------------------------------------
// Kernel 3: recurrent LSTMs via MFMA (gb-roundtrip dedup nonlinearity) +
// fused MLP head. 256 blocks x 512 threads; 2 seqs/block. gx in LDS.
// ---------------------------------------------------------------------------
__global__ __launch_bounds__(512, 2) void lstm_head_kernel(
    const char* ws_ro, const _Float16* gx,
    const float* b1, const float* W2, const float* b2,
    float* out_kp) {
  const f16x8* fehh   = (const f16x8*)(ws_ro + OFF_FEHH);
  const uint2* fdih8  = (const uint2*)(ws_ro + OFF_FDIH8);
  const uint2* fdhh8  = (const uint2*)(ws_ro + OFF_FDHH8);
  const float* bias_d = (const float*)(ws_ro + OFF_BIAS_D);
  const uint32_t* W1h = (const uint32_t*)(ws_ro + OFF_W1H);

  __shared__ __attribute__((aligned(16))) uint32_t gxs[2][32][256];   // 64 KB
  __shared__ __attribute__((aligned(16))) uint32_t enc8[2][32][32];   //  8 KB
  __shared__ __attribute__((aligned(16))) uint32_t dech2[2][32][64];  // 16 KB
  __shared__ __attribute__((aligned(16))) uint32_t hb2[2][64];        // 512 B
  __shared__ __attribute__((aligned(16))) uint32_t hb8[2][32];        // 256 B
  __shared__ __attribute__((aligned(16))) float    gb[2][512];        //  4 KB
  __shared__ float hidf[64][65];                                      // 16.6 KB

  int tid  = threadIdx.x;
  int lane = tid & 63, wave = tid >> 6;
  int col  = lane & 15, lgrp = lane >> 4;
  int bn0  = blockIdx.x * 2;

  int s_nl = tid >> 7, u_nl = tid & 127;
  float c_reg = 0.0f;

  {
    const uint32_t* gxu = (const uint32_t*)(gx + (size_t)bn0*32*512);
    for (int i = tid; i < 8192; i += 512)
      ((uint32_t*)gxs)[i] = gxu[i];
  }

  f16x8 ae[4][4];
  #pragma unroll
  for (int g0 = 0; g0 < 4; ++g0)
    #pragma unroll
    for (int kt = 0; kt < 4; ++kt)
      ae[g0][kt] = fehh[((wave*4 + g0)*4 + kt)*64 + lane];

  if (tid < 128) hb2[tid >> 6][tid & 63] = 0u;
  __syncthreads();

  const f16x8 bzero = {};

  // ----------------- encoder -----------------
  for (int t = 0; t < 32; ++t) {
    f16x8 bf[4];
    #pragma unroll
    for (int kt = 0; kt < 4; ++kt) {
      if (col < 2) bf[kt] = *(const f16x8*)&hb2[col][kt*16 + lgrp*4];
      else         bf[kt] = bzero;
    }
    #pragma unroll
    for (int g0 = 0; g0 < 4; ++g0) {
      f32x4 acc = {0.f, 0.f, 0.f, 0.f};
      #pragma unroll
      for (int kt = 0; kt < 4; ++kt)
        acc = __builtin_amdgcn_mfma_f32_16x16x32_f16(ae[g0][kt], bf[kt], acc, 0, 0, 0);
      if (col < 2)
        *(f32x4*)&gb[col][(wave*4 + g0)*16 + lgrp*4] = acc;
    }
    __syncthreads();
    if (tid < 256) {
      const _Float16* gr = (const _Float16*)&gxs[s_nl][t][0];
      float ig = sig_ (gb[s_nl][u_nl]       + (float)gr[u_nl]);
      float fg = sig_ (gb[s_nl][128 + u_nl] + (float)gr[128 + u_nl]);
      float gg = tanh_(gb[s_nl][256 + u_nl] + (float)gr[256 + u_nl]);
      float og = sig_ (gb[s_nl][384 + u_nl] + (float)gr[384 + u_nl]);
      c_reg = fg * c_reg + ig * gg;
      float hh = og * tanh_(c_reg);
      ((_Float16*)&hb2[s_nl][0])[u_nl] = (_Float16)hh;
      ((uint8_t*)&enc8[s_nl][t][0])[u_nl] = f8_(hh);
    }
    __syncthreads();
  }

  if (tid < 256) {
    float hv = (float)((_Float16*)&hb2[s_nl][0])[u_nl];
    ((uint8_t*)&hb8[s_nl][0])[u_nl] = f8_(hv);
  }

  uint2 dih8[4][4], dhh8[4][4];
  #pragma unroll
  for (int g0 = 0; g0 < 4; ++g0)
    #pragma unroll
    for (int kt = 0; kt < 4; ++kt) {
      dih8[g0][kt] = ldg_frag8(&fdih8[((wave*4 + g0)*4 + kt)*64 + lane]);
      dhh8[g0][kt] = ldg_frag8(&fdhh8[((wave*4 + g0)*4 + kt)*64 + lane]);
    }
  frag_fence();
  float bdi = 0.f, bdf = 0.f, bdg = 0.f, bdo = 0.f;
  if (tid < 256) {
    bdi = bias_d[u_nl];       bdf = bias_d[128 + u_nl];
    bdg = bias_d[256 + u_nl]; bdo = bias_d[384 + u_nl];
  }
  __syncthreads();

  // ----------------- decoder (fp8 MFMA) -----------------
  for (int t = 0; t < 32; ++t) {
    long bx[4], bh[4];
    #pragma unroll
    for (int kt = 0; kt < 4; ++kt) {
      if (col < 2) {
        bx[kt] = u2l(*(const uint2*)&enc8[col][t][kt*8 + lgrp*2]);
        bh[kt] = u2l(*(const uint2*)&hb8[col][kt*8 + lgrp*2]);
      } else { bx[kt] = 0; bh[kt] = 0; }
    }
    #pragma unroll
    for (int g0 = 0; g0 < 4; ++g0) {
      f32x4 acc = {0.f, 0.f, 0.f, 0.f};
      #pragma unroll
      for (int kt = 0; kt < 4; ++kt)
        acc = __builtin_amdgcn_mfma_f32_16x16x32_fp8_fp8(
            u2l(dih8[g0][kt]), bx[kt], acc, 0, 0, 0);
      #pragma unroll
      for (int kt = 0; kt < 4; ++kt)
        acc = __builtin_amdgcn_mfma_f32_16x16x32_fp8_fp8(
            u2l(dhh8[g0][kt]), bh[kt], acc, 0, 0, 0);
      if (col < 2)
        *(f32x4*)&gb[col][(wave*4 + g0)*16 + lgrp*4] = acc;
    }
    __syncthreads();
    if (tid < 256) {
      float ig = sig_ (gb[s_nl][u_nl]       + bdi);
      float fg = sig_ (gb[s_nl][128 + u_nl] + bdf);
      float gg = tanh_(gb[s_nl][256 + u_nl] + bdg);
      float og = sig_ (gb[s_nl][384 + u_nl] + bdo);
      c_reg = fg * c_reg + ig * gg;
      float hh = og * tanh_(c_reg);
      ((uint8_t*)&hb8[s_nl][0])[u_nl] = f8_(hh);
      ((_Float16*)&dech2[s_nl][t][0])[u_nl] = (_Float16)hh;
    }
    __syncthreads();
  }

  // ----------------- fused head -----------------
  {
    int j = tid & 63, w = tid >> 6;
    float acc[8];
    #pragma unroll
    for (int m = 0; m < 8; ++m) acc[m] = b1[j];
    #pragma unroll 8
    for (int k = 0; k < 64; ++k) {
      uint32_t wv = W1h[k*64 + j];
      #pragma unroll
      for (int m = 0; m < 8; ++m) {
        int st = w + 8*m;
        acc[m] = fdot2_(wv, dech2[st >> 5][st & 31][k], acc[m]);
      }
    }
    #pragma unroll
    for (int m = 0; m < 8; ++m) {
      int st = w + 8*m;
      hidf[st][j] = fmaxf(acc[m], 0.0f);
    }
  }
  __syncthreads();
  if (tid < 128) {
    int st = tid >> 1, e = tid & 1;
    float acc = b2[e];
    #pragma unroll 16
    for (int j = 0; j < 64; ++j) acc += W2[e*64 + j] * hidf[st][j];
    int s = st >> 5, t = st & 31;
    out_kp[((bn0 + s)*32 + t)*2 + e] = acc;
  }
}

// ---------------------------------------------------------------------------
// Launch
// ---------------------------------------------------------------------------
extern "C" void kernel_launch(void* const* d_in, const int* in_sizes, int n_in,
                              void* d_out, int out_size, void* d_ws, size_t ws_size,
                              hipStream_t stream) {
  const float* x          = (const float*)d_in[0];
  const float* mask_point = (const float*)d_in[1];
  const int*   point_mask = (const int*)d_in[2];
  const float* conv1_w    = (const float*)d_in[3];
  const float* conv1_b    = (const float*)d_in[4];
  const float* conv2_w    = (const float*)d_in[5];
  const float* conv2_b    = (const float*)d_in[6];
  const float* Wih_e      = (const float*)d_in[7];
  const float* Whh_e      = (const float*)d_in[8];
  const float* bih_e      = (const float*)d_in[9];
  const float* bhh_e      = (const float*)d_in[10];
  const float* Wih_d      = (const float*)d_in[11];
  const float* Whh_d      = (const float*)d_in[12];
  const float* bih_d      = (const float*)d_in[13];
  const float* bhh_d      = (const float*)d_in[14];
  const float* W1         = (const float*)d_in[15];
  const float* b1         = (const float*)d_in[16];
  const float* W2         = (const float*)d_in[17];
  const float* b2         = (const float*)d_in[18];

  float* out = (float*)d_out;
  char*  ws  = (char*)d_ws;

  const bool use_xt = (ws_size >= WS_NEED_XT);
  _Float16* gx = (_Float16*)(ws + (use_xt ? OFF_XT : OFF_GX_FB));

  prep_kernel<<<(PREP_TOTAL + 255)/256, 256, 0, stream>>>(
      Wih_e, Whh_e, bih_e, bhh_e, Wih_d, Whh_d, bih_d, bhh_d,
      conv1_w, conv2_w, W1, mask_point, out + 32768, (int*)(ws + OFF_FLAT),
      ws, use_xt ? 1 : 0);

  if (use_xt) {
    transpose_kernel<<<1024, 256, 0, stream>>>(x, (uint32_t*)(ws + OFF_XT));
    conv_mfma_kernel<<<256, 512, 0, stream>>>(
        (const uint32_t*)(ws + OFF_XT), point_mask, conv1_b, conv2_b,
        ws, (_Float16*)(ws + OFF_DOTS), (const int*)(ws + OFF_FLAT));
  } else {
    conv_gather_kernel<<<512, 256, 0, stream>>>(
        x, point_mask, conv1_b, conv2_b,
        ws, (_Float16*)(ws + OFF_DOTS), (const int*)(ws + OFF_FLAT));
  }

  gx_gemm_kernel<<<512, 512, 0, stream>>>(ws, gx);

  lstm_head_kernel<<<256, 512, 0, stream>>>(ws, gx, b1, W2, b2, out);
}

// Round 15
// 121.291 us; speedup vs baseline: 1.3921x; 1.1253x over previous
//
#include <hip/hip_runtime.h>
#include <stdint.h>

// ---------------------------------------------------------------------------
// Problem constants
// ---------------------------------------------------------------------------
#define NSEQ 512        // B*N
#define HIDN 128

// ws byte offsets
#define OFF_FEIH   0                            // enc Wih f16 frags (32gt x 2kt), 64 KB
#define OFF_BIAS_E 65536                        // 512 f32
#define OFF_BIAS_D 67584                        // 512 f32
#define OFF_W1P    69632                        // conv w1 f16 pairs [288][64]
#define OFF_W2P    143360                       // conv w2 f16 pairs [32][64]
#define OFF_FLAT   151552                       // [16384] int
#define OFF_W1H    217088                       // head W1 f16 pairs [64][64]
#define OFF_FEHH   233472                       // enc Whh f16 frags, 128 KB
#define OFF_FDIH8  364544                       // dec Wih fp8 frags, 64 KB
#define OFF_FDHH8  430080                       // dec Whh fp8 frags, 64 KB
#define OFF_W2T    495616                       // conv w2 frags [64][36] u32 = 9216 B
#define OFF_DOTS   (1024*1024)                  // [32][512][64] f16 = 2 MB
#define OFF_XT     (4*1024*1024)                // xT f16 = 33.5 MB
#define WS_NEED_XT ((size_t)(4*1024*1024) + (size_t)16*128*128*64*2 + 1024)

typedef _Float16 h2f __attribute__((ext_vector_type(2)));
typedef _Float16 f16x8 __attribute__((ext_vector_type(8)));
typedef float    f32x4 __attribute__((ext_vector_type(4)));

static __device__ __forceinline__ h2f u2h(uint32_t u) {
  union { uint32_t u; h2f h; } v; v.u = u; return v.h;
}

#if __has_builtin(__builtin_amdgcn_fdot2)
static __device__ __forceinline__ float fdot2_(uint32_t a, uint32_t b, float c) {
  return __builtin_amdgcn_fdot2(u2h(a), u2h(b), c, false);
}
#else
static __device__ __forceinline__ float fdot2_(uint32_t a, uint32_t b, float c) {
  h2f x = u2h(a), y = u2h(b);
  return c + (float)x.x * (float)y.x + (float)x.y * (float)y.y;
}
#endif

static __device__ __forceinline__ uint32_t packh(float a, float b) {
  union { _Float16 h[2]; uint32_t u; } v;
  v.h[0] = (_Float16)a; v.h[1] = (_Float16)b; return v.u;
}
static __device__ __forceinline__ float sig_(float x) {
  return 1.0f / (1.0f + __expf(-x));
}
static __device__ __forceinline__ float tanh_(float x) {
  return 1.0f - 2.0f / (1.0f + __expf(2.0f * x));
}

// ---- fp8 e4m3fn helpers ----------------------------------------------------
static __device__ __forceinline__ uint32_t f2e4m3_sw(float f) {
  union { float f; uint32_t u; } v; v.f = f;
  uint32_t s = (v.u >> 24) & 0x80u;
  float af = fabsf(f);
  if (af == 0.0f) return s;
  if (af >= 448.0f) return s | 0x7Eu;
  int e; float m = frexpf(af, &e);      // af = m*2^e, m in [0.5,1)
  int E = e + 6;                         // 1.xxx*2^(e-1), bias 7
  float mant = m * 2.0f - 1.0f;
  int mm = (int)(mant * 8.0f + 0.5f);
  if (mm == 8) { mm = 0; ++E; }
  if (E < 1) {                           // subnormal: step 2^-9
    int sm = (int)(af * 512.0f + 0.5f);
    return s | (uint32_t)(sm > 7 ? 7 : sm);
  }
  if (E > 15) return s | 0x7Eu;
  return s | ((uint32_t)E << 3) | (uint32_t)mm;
}
static __device__ __forceinline__ uint32_t pk4_fp8(float a, float b, float c, float d) {
#if __has_builtin(__builtin_amdgcn_cvt_pk_fp8_f32)
  int r = __builtin_amdgcn_cvt_pk_fp8_f32(a, b, 0, false);
  r = __builtin_amdgcn_cvt_pk_fp8_f32(c, d, r, true);
  return (uint32_t)r;
#else
  return f2e4m3_sw(a) | (f2e4m3_sw(b) << 8) | (f2e4m3_sw(c) << 16) | (f2e4m3_sw(d) << 24);
#endif
}
static __device__ __forceinline__ uint8_t f8_(float v) {
#if __has_builtin(__builtin_amdgcn_cvt_pk_fp8_f32)
  return (uint8_t)(__builtin_amdgcn_cvt_pk_fp8_f32(v, 0.f, 0, false) & 0xFF);
#else
  return (uint8_t)f2e4m3_sw(v);
#endif
}
static __device__ __forceinline__ long u2l(uint2 v) {
  union { uint2 v; long l; } x; x.v = v; return x.l;
}
// pinned 8B load (asm-produced -> non-rematerializable)
static __device__ __forceinline__ uint2 ldg_frag8(const uint2* p) {
  uint2 r;
  asm volatile("global_load_dwordx2 %0, %1, off" : "=v"(r) : "v"(p));
  return r;
}
static __device__ __forceinline__ void frag_fence() {
  asm volatile("s_waitcnt vmcnt(0)" ::: "memory");
  __builtin_amdgcn_sched_barrier(0);
}

// ---------------------------------------------------------------------------
// Kernel 0: weight prep + point math.
// f16 A-frag (16x16x32): lane l holds A[row=l&15][k=(l>>4)*8+j], j=0..7.
// PLAIN tiling: g = gt*16 + (l&15); k = kt*32 + ((l>>4)&3)*8 + ...
// fp8 frags use the same map with 8 fp8 bytes (2 VGPRs).
// ---------------------------------------------------------------------------
__global__ __launch_bounds__(256) void prep_kernel(
    const float* Wih_e, const float* Whh_e,
    const float* bih_e, const float* bhh_e,
    const float* Wih_d, const float* Whh_d,
    const float* bih_d, const float* bhh_d,
    const float* w1, const float* w2, const float* W1,
    const float* mask_point, float* out_gt, int* flat,
    char* ws, int w1_order) {
  float*    bias_e = (float*)(ws + OFF_BIAS_E);
  float*    bias_d = (float*)(ws + OFF_BIAS_D);
  uint32_t* w1p    = (uint32_t*)(ws + OFF_W1P);
  uint32_t* w2p    = (uint32_t*)(ws + OFF_W2P);
  uint32_t* W1h    = (uint32_t*)(ws + OFF_W1H);
  uint32_t* w2t    = (uint32_t*)(ws + OFF_W2T);

  int idx = blockIdx.x * 256 + threadIdx.x;
  if (idx < 16384) {                              // feih: enc Wih frags (K=64)
    int j2 = idx & 3, lane = (idx >> 2) & 63, kt = (idx >> 8) & 1, gt = idx >> 9;
    int g = gt*16 + (lane & 15);
    int k = kt*32 + ((lane >> 4) & 3)*8 + 2*j2;
    ((uint32_t*)(ws + OFF_FEIH))[idx] = packh(Wih_e[g*64 + k], Wih_e[g*64 + k + 1]);
    return;
  }
  idx -= 16384;
  if (idx < 512) { bias_e[idx] = bih_e[idx] + bhh_e[idx]; return; }
  idx -= 512;
  if (idx < 512) { bias_d[idx] = bih_d[idx] + bhh_d[idx]; return; }
  idx -= 512;
  if (idx < 288*64) {                             // conv w1 pairs [i2][c]
    int i2 = idx >> 6, c = idx & 63;
    if (w1_order) {
      int tap = i2 >> 5, cin = (i2 & 31) * 2;     // i2 = tap*32 + c2
      w1p[idx] = packh(w1[c*576 + cin*9 + tap], w1[c*576 + (cin+1)*9 + tap]);
    } else {
      w1p[idx] = packh(w1[c*576 + 2*i2], w1[c*576 + 2*i2 + 1]);
    }
    return;
  }
  idx -= 288*64;
  if (idx < 32*64) {                              // conv w2 pairs [c2][d]
    int c2 = idx >> 6, d = idx & 63;
    w2p[idx] = packh(w2[d*64 + 2*c2], w2[d*64 + 2*c2 + 1]);
    return;
  }
  idx -= 32*64;
  if (idx < 64*64) {                              // head W1 pairs [k2][j]
    int k2 = idx >> 6, j = idx & 63;
    W1h[idx] = packh(W1[j*128 + 2*k2], W1[j*128 + 2*k2 + 1]);
    return;
  }
  idx -= 64*64;
  if (idx < 32768) {                              // fehh f16 frags
    int j2 = idx & 3, lane = (idx >> 2) & 63, kt = (idx >> 8) & 3, gt = idx >> 10;
    int g = gt*16 + (lane & 15);
    int k = kt*32 + ((lane >> 4) & 3)*8 + 2*j2;
    ((uint32_t*)(ws + OFF_FEHH))[idx] = packh(Whh_e[g*128 + k], Whh_e[g*128 + k + 1]);
    return;
  }
  idx -= 32768;
  if (idx < 16384) {                              // fdih8 fp8 frags
    int half = idx & 1, lane = (idx >> 1) & 63, kt = (idx >> 7) & 3, gt = idx >> 9;
    int g = gt*16 + (lane & 15);
    int kb = kt*32 + ((lane >> 4) & 3)*8 + half*4;
    const float* W = Wih_d;
    ((uint32_t*)(ws + OFF_FDIH8))[(((gt*4 + kt)*64 + lane) << 1) | half] =
        pk4_fp8(W[g*128 + kb], W[g*128 + kb + 1], W[g*128 + kb + 2], W[g*128 + kb + 3]);
    return;
  }
  idx -= 16384;
  if (idx < 16384) {                              // fdhh8 fp8 frags
    int half = idx & 1, lane = (idx >> 1) & 63, kt = (idx >> 7) & 3, gt = idx >> 9;
    int g = gt*16 + (lane & 15);
    int kb = kt*32 + ((lane >> 4) & 3)*8 + half*4;
    const float* W = Whh_d;
    ((uint32_t*)(ws + OFF_FDHH8))[(((gt*4 + kt)*64 + lane) << 1) | half] =
        pk4_fp8(W[g*128 + kb], W[g*128 + kb + 1], W[g*128 + kb + 2], W[g*128 + kb + 3]);
    return;
  }
  idx -= 16384;
  if (idx < 64*36) {                              // w2t [d][c2] pad 36 (MFMA A)
    int d = idx / 36, c2 = idx - (idx/36)*36;
    w2t[idx] = (c2 < 32) ? packh(w2[d*64 + 2*c2], w2[d*64 + 2*c2 + 1]) : 0u;
    return;
  }
  idx -= 64*36;
  if (idx < 16384) {                              // point math -> gt + flat
    float mx = mask_point[idx*2 + 0];
    float my = mask_point[idx*2 + 1];
    float fx = fminf(mx * 0.25f, 127.0f);
    float fy = fminf(my * 0.25f, 127.0f);
    out_gt[idx*2 + 0] = fx * 4.0f;
    out_gt[idx*2 + 1] = fy * 4.0f;
    flat[idx] = (int)(__fmaf_rn(fy, 128.0f, fx)); // fy*128 exact
    return;
  }
}
#define PREP_TOTAL (16384 + 512 + 512 + 288*64 + 32*64 + 64*64 + 32768 + 16384 + 16384 + 64*36 + 16384)

// ---------------------------------------------------------------------------
// Kernel T: x [16][64][128][128] f32 -> xT [16][128][128][64] f16 (NHWC)
// ---------------------------------------------------------------------------
__global__ __launch_bounds__(256, 2) void transpose_kernel(
    const float* x, uint32_t* xT32) {
  __shared__ float lds[64][257];
  int bid = blockIdx.x;           // 1024 = 16 b x 16 yt x 4 xt
  int xt = bid & 3, yt = (bid >> 2) & 15, b = bid >> 6;
  int x0 = xt * 32, y0 = yt * 8;
  int tx = threadIdx.x & 31, ty = threadIdx.x >> 5;
  #pragma unroll 8
  for (int c = 0; c < 64; ++c)
    lds[c][ty*32 + tx] = x[((b*64 + c)*128 + (y0 + ty))*128 + (x0 + tx)];
  __syncthreads();
  #pragma unroll 8
  for (int r = 0; r < 32; ++r) {
    int i = threadIdx.x + 256*r;    // i = pos*32 + c2
    int c2 = i & 31, pos = i >> 5;
    int yy = pos >> 5, xx = pos & 31;
    float lo = lds[2*c2][yy*32 + xx], hi = lds[2*c2 + 1][yy*32 + xx];
    xT32[((b*128 + y0 + yy)*128 + (x0 + xx))*32 + c2] = packh(lo, hi);
  }
}

// ---------------------------------------------------------------------------
// Kernel 2 (MFMA): gathered conv (3x3 -> ReLU -> 1x1) at points.
// 256 blocks x 512 threads (8 waves); 64 points/block in 2 iters of 32.
// ---------------------------------------------------------------------------
__global__ __launch_bounds__(512, 1) void conv_mfma_kernel(
    const uint32_t* xT32, const int* point_mask,
    const float* conv1_b, const float* conv2_b,
    const char* ws_ro, _Float16* dots_h, const int* flat) {
  __shared__ __attribute__((aligned(16))) uint32_t w1s[64*292];    // 74752 B
  __shared__ __attribute__((aligned(16))) uint32_t patch2[32*292]; // 37376 B
  __shared__ __attribute__((aligned(16))) uint32_t t1s[32*36];     //  4608 B

  const uint32_t* w1p = (const uint32_t*)(ws_ro + OFF_W1P);
  const uint32_t* w2t = (const uint32_t*)(ws_ro + OFF_W2T);
  int tid  = threadIdx.x;
  int lane = tid & 63, wave = tid >> 6;
  int r = wave & 3, g = wave >> 2;      // row-tile (channels), point-group
  int cl = lane & 15, lgrp = lane >> 4;

  for (int i = tid; i < 288*64; i += 512) {
    int i2 = i >> 6, cc = i & 63;
    w1s[cc*292 + i2] = w1p[i];
  }

  // conv2 A-frags (held in registers; rows d = r*16+cl)
  uint4 a2[2];
  #pragma unroll
  for (int kt = 0; kt < 2; ++kt)
    a2[kt] = *(const uint4*)&w2t[(r*16 + cl)*36 + kt*16 + lgrp*4];

  float4 b1v = *(const float4*)&conv1_b[r*16 + lgrp*4];
  float4 b2v = *(const float4*)&conv2_b[r*16 + lgrp*4];

  for (int it = 0; it < 2; ++it) {
    int p0 = blockIdx.x * 64 + it * 32;
    __syncthreads();                    // patch2/t1s reuse (+ w1s ready, it=0)
    #pragma unroll
    for (int rr = 0; rr < 18; ++rr) {   // 9216 u32 = 32 slots x 288
      int u = tid + 512*rr;
      int slot = u / 288, w = u - slot*288;
      int tap = w >> 5, c2i = w & 31;
      int p = p0 + slot;
      int fl = flat[p];
      int hh = fl >> 7, ww = fl & 127;
      int b = p >> 10;
      int dy = tap / 3, dx = tap - dy*3;
      int yy = hh + dy - 1, xx = ww + dx - 1;
      uint32_t v = 0u;
      if (yy >= 0 && yy < 128 && xx >= 0 && xx < 128)
        v = xT32[((b*128 + yy)*128 + xx)*32 + c2i];
      patch2[slot*292 + w] = v;
    }
    __syncthreads();

    // conv1 MFMA: 18 k-tiles
    f32x4 acc = {b1v.x, b1v.y, b1v.z, b1v.w};
    #pragma unroll
    for (int kt = 0; kt < 18; ++kt) {
      f16x8 af = *(const f16x8*)&w1s[(r*16 + cl)*292 + kt*16 + lgrp*4];
      f16x8 bf = *(const f16x8*)&patch2[(g*16 + cl)*292 + kt*16 + lgrp*4];
      acc = __builtin_amdgcn_mfma_f32_16x16x32_f16(af, bf, acc, 0, 0, 0);
    }
    // relu -> t1 (f16)
    {
      int trow = (g*16 + cl)*36 + r*8 + lgrp*2;
      t1s[trow]     = packh(fmaxf(acc[0], 0.f), fmaxf(acc[1], 0.f));
      t1s[trow + 1] = packh(fmaxf(acc[2], 0.f), fmaxf(acc[3], 0.f));
    }
    __syncthreads();

    // conv2 MFMA: 2 k-tiles
    f32x4 acc2 = {b2v.x, b2v.y, b2v.z, b2v.w};
    #pragma unroll
    for (int kt = 0; kt < 2; ++kt) {
      f16x8 af; __builtin_memcpy(&af, &a2[kt], 16);
      f16x8 bf = *(const f16x8*)&t1s[(g*16 + cl)*36 + kt*16 + lgrp*4];
      acc2 = __builtin_amdgcn_mfma_f32_16x16x32_f16(af, bf, acc2, 0, 0, 0);
    }
    {
      int p = p0 + g*16 + cl;
      float m = (float)point_mask[p];
      int kk = p & 31, bn = p >> 5;
      int d0 = r*16 + lgrp*4;
      uint2 o;
      o.x = packh(acc2[0]*m, acc2[1]*m);
      o.y = packh(acc2[2]*m, acc2[3]*m);
      *(uint2*)&dots_h[(size_t)(kk*NSEQ + bn)*64 + d0] = o;
    }
  }
}

// ---------------------------------------------------------------------------
// Kernel 2 fallback (no xT): scalar gathered conv from NCHW f32.
// ---------------------------------------------------------------------------
__global__ __launch_bounds__(256, 2) void conv_gather_kernel(
    const float* x, const int* point_mask,
    const float* conv1_b, const float* conv2_b,
    const char* ws_ro, _Float16* dots_h, const int* flat) {
  __shared__ uint32_t w1s[64*292];
  __shared__ uint32_t patch2[4*288];
  __shared__ uint32_t tl2[4*32];

  const uint32_t* w1p = (const uint32_t*)(ws_ro + OFF_W1P);
  const uint32_t* w2p = (const uint32_t*)(ws_ro + OFF_W2P);
  int tid = threadIdx.x;
  for (int i = tid; i < 288*64; i += 256) {
    int i2 = i >> 6, cc = i & 63;
    w1s[cc*292 + i2] = w1p[i];
  }

  int q = tid >> 6, c = tid & 63;
  float c1b = conv1_b[c], c2b = conv2_b[c];

  for (int g = 0; g < 8; ++g) {
    int p0 = blockIdx.x * 32 + g * 4;
    __syncthreads();
    #pragma unroll
    for (int r = 0; r < 9; ++r) {
      int l = tid + 256*r;
      int slot = l / 576;
      int within = l - slot*576;
      int cp = within / 9;
      int tap = within - cp*9;
      int p = p0 + slot;
      int fl = flat[p];
      int hh = fl >> 7, ww = fl & 127;
      int b = p >> 10;
      int yy = hh + tap/3 - 1, xx = ww + tap%3 - 1;
      float v = 0.0f;
      if (yy >= 0 && yy < 128 && xx >= 0 && xx < 128)
        v = x[((b*64 + cp)*128 + yy)*128 + xx];
      ((_Float16*)patch2)[l] = (_Float16)v;
    }
    __syncthreads();

    float a0 = c1b, a1 = 0.f, a2 = 0.f, a3 = 0.f;
    int cbase = c * 292, pbase = q * 288;
    #pragma unroll 4
    for (int i2 = 0; i2 < 288; i2 += 4) {
      a0 = fdot2_(w1s[cbase + i2+0], patch2[pbase + i2+0], a0);
      a1 = fdot2_(w1s[cbase + i2+1], patch2[pbase + i2+1], a1);
      a2 = fdot2_(w1s[cbase + i2+2], patch2[pbase + i2+2], a2);
      a3 = fdot2_(w1s[cbase + i2+3], patch2[pbase + i2+3], a3);
    }
    float t1 = fmaxf((a0 + a1) + (a2 + a3), 0.0f);
    ((_Float16*)tl2)[q*64 + c] = (_Float16)t1;

    float acc2 = c2b;
    #pragma unroll
    for (int c2i = 0; c2i < 32; ++c2i)
      acc2 = fdot2_(w2p[c2i*64 + c], tl2[q*32 + c2i], acc2);
    int p = p0 + q;
    acc2 *= (float)point_mask[p];
    int k = p & 31, bn = p >> 5;
    dots_h[(k*NSEQ + bn)*64 + c] = (_Float16)acc2;
  }
}

// ---------------------------------------------------------------------------
// Kernel 3: recurrent LSTMs via MFMA (gb-roundtrip dedup nonlinearity) +
// fused MLP head. 256 blocks x 512 threads; 2 seqs/block.
// Encoder: f16 MFMA with x-projection FUSED (feih 2 kt + fehh 4 kt); x staged
// from dots into 8 KB LDS; bias_e applied at nonlinearity.
// Decoder: fp8 MFMA (32 asm-pinned frags); h as fp8 bytes in LDS.
// ---------------------------------------------------------------------------
__global__ __launch_bounds__(512, 2) void lstm_head_kernel(
    const char* ws_ro,
    const float* b1, const float* W2, const float* b2,
    float* out_kp) {
  const f16x8* feih   = (const f16x8*)(ws_ro + OFF_FEIH);
  const f16x8* fehh   = (const f16x8*)(ws_ro + OFF_FEHH);
  const uint2* fdih8  = (const uint2*)(ws_ro + OFF_FDIH8);
  const uint2* fdhh8  = (const uint2*)(ws_ro + OFF_FDHH8);
  const float* bias_e = (const float*)(ws_ro + OFF_BIAS_E);
  const float* bias_d = (const float*)(ws_ro + OFF_BIAS_D);
  const uint32_t* dots_u = (const uint32_t*)(ws_ro + OFF_DOTS);
  const uint32_t* W1h = (const uint32_t*)(ws_ro + OFF_W1H);

  __shared__ __attribute__((aligned(16))) uint32_t xs[2][32][32];     //  8 KB f16
  __shared__ __attribute__((aligned(16))) uint32_t enc8[2][32][32];   //  8 KB fp8
  __shared__ __attribute__((aligned(16))) uint32_t dech2[2][32][64];  // 16 KB f16
  __shared__ __attribute__((aligned(16))) uint32_t hb2[2][64];        // 512 B f16
  __shared__ __attribute__((aligned(16))) uint32_t hb8[2][32];        // 256 B fp8
  __shared__ __attribute__((aligned(16))) float    gb[2][512];        //  4 KB
  __shared__ float hidf[64][65];                                      // 16.6 KB

  int tid  = threadIdx.x;
  int lane = tid & 63, wave = tid >> 6;
  int col  = lane & 15, lgrp = lane >> 4;
  int sb   = col & 1;
  int bn0  = blockIdx.x * 2;

  int s_nl = tid >> 7, u_nl = tid & 127;    // nonlinearity role (tid < 256)
  float c_reg = 0.0f;

  // stage x (dots) for both seqs: 8 KB
  for (int i = tid; i < 2048; i += 512) {
    int s = i >> 10, rem = i & 1023, t = rem >> 5, k2 = rem & 31;
    xs[s][t][k2] = dots_u[(t*NSEQ + bn0 + s)*32 + k2];
  }

  // encoder weights: x-proj (8 frags) + h (16 frags)
  f16x8 ax[4][2], ae[4][4];
  #pragma unroll
  for (int g0 = 0; g0 < 4; ++g0) {
    #pragma unroll
    for (int kt = 0; kt < 2; ++kt)
      ax[g0][kt] = feih[((wave*4 + g0)*2 + kt)*64 + lane];
    #pragma unroll
    for (int kt = 0; kt < 4; ++kt)
      ae[g0][kt] = fehh[((wave*4 + g0)*4 + kt)*64 + lane];
  }

  // bias_e for nonlinearity threads (valid index for all tids)
  float be0 = bias_e[u_nl],       be1 = bias_e[128 + u_nl];
  float be2 = bias_e[256 + u_nl], be3 = bias_e[384 + u_nl];

  if (tid < 128) hb2[tid >> 6][tid & 63] = 0u;
  __syncthreads();

  const f16x8 bzero = {};

  // ----------------- encoder -----------------
  for (int t = 0; t < 32; ++t) {
    f16x8 bx[2], bf[4];
    #pragma unroll
    for (int kt = 0; kt < 2; ++kt)
      bx[kt] = *(const f16x8*)&xs[sb][t][kt*16 + lgrp*4];   // broadcast
    #pragma unroll
    for (int kt = 0; kt < 4; ++kt) {
      if (col < 2) bf[kt] = *(const f16x8*)&hb2[col][kt*16 + lgrp*4];
      else         bf[kt] = bzero;
    }
    #pragma unroll
    for (int g0 = 0; g0 < 4; ++g0) {
      f32x4 acc = {0.f, 0.f, 0.f, 0.f};
      #pragma unroll
      for (int kt = 0; kt < 2; ++kt)
        acc = __builtin_amdgcn_mfma_f32_16x16x32_f16(ax[g0][kt], bx[kt], acc, 0, 0, 0);
      #pragma unroll
      for (int kt = 0; kt < 4; ++kt)
        acc = __builtin_amdgcn_mfma_f32_16x16x32_f16(ae[g0][kt], bf[kt], acc, 0, 0, 0);
      if (col < 2)
        *(f32x4*)&gb[col][(wave*4 + g0)*16 + lgrp*4] = acc;
    }
    __syncthreads();
    if (tid < 256) {
      float ig = sig_ (gb[s_nl][u_nl]       + be0);
      float fg = sig_ (gb[s_nl][128 + u_nl] + be1);
      float gg = tanh_(gb[s_nl][256 + u_nl] + be2);
      float og = sig_ (gb[s_nl][384 + u_nl] + be3);
      c_reg = fg * c_reg + ig * gg;
      float hh = og * tanh_(c_reg);
      ((_Float16*)&hb2[s_nl][0])[u_nl] = (_Float16)hh;
      ((uint8_t*)&enc8[s_nl][t][0])[u_nl] = f8_(hh);
    }
    __syncthreads();
  }

  if (tid < 256) {
    float hv = (float)((_Float16*)&hb2[s_nl][0])[u_nl];
    ((uint8_t*)&hb8[s_nl][0])[u_nl] = f8_(hv);
  }

  uint2 dih8[4][4], dhh8[4][4];
  #pragma unroll
  for (int g0 = 0; g0 < 4; ++g0)
    #pragma unroll
    for (int kt = 0; kt < 4; ++kt) {
      dih8[g0][kt] = ldg_frag8(&fdih8[((wave*4 + g0)*4 + kt)*64 + lane]);
      dhh8[g0][kt] = ldg_frag8(&fdhh8[((wave*4 + g0)*4 + kt)*64 + lane]);
    }
  frag_fence();
  float bdi = 0.f, bdf = 0.f, bdg = 0.f, bdo = 0.f;
  if (tid < 256) {
    bdi = bias_d[u_nl];       bdf = bias_d[128 + u_nl];
    bdg = bias_d[256 + u_nl]; bdo = bias_d[384 + u_nl];
  }
  __syncthreads();

  // ----------------- decoder (fp8 MFMA) -----------------
  for (int t = 0; t < 32; ++t) {
    long bx[4], bh[4];
    #pragma unroll
    for (int kt = 0; kt < 4; ++kt) {
      if (col < 2) {
        bx[kt] = u2l(*(const uint2*)&enc8[col][t][kt*8 + lgrp*2]);
        bh[kt] = u2l(*(const uint2*)&hb8[col][kt*8 + lgrp*2]);
      } else { bx[kt] = 0; bh[kt] = 0; }
    }
    #pragma unroll
    for (int g0 = 0; g0 < 4; ++g0) {
      f32x4 acc = {0.f, 0.f, 0.f, 0.f};
      #pragma unroll
      for (int kt = 0; kt < 4; ++kt)
        acc = __builtin_amdgcn_mfma_f32_16x16x32_fp8_fp8(
            u2l(dih8[g0][kt]), bx[kt], acc, 0, 0, 0);
      #pragma unroll
      for (int kt = 0; kt < 4; ++kt)
        acc = __builtin_amdgcn_mfma_f32_16x16x32_fp8_fp8(
            u2l(dhh8[g0][kt]), bh[kt], acc, 0, 0, 0);
      if (col < 2)
        *(f32x4*)&gb[col][(wave*4 + g0)*16 + lgrp*4] = acc;
    }
    __syncthreads();
    if (tid < 256) {
      float ig = sig_ (gb[s_nl][u_nl]       + bdi);
      float fg = sig_ (gb[s_nl][128 + u_nl] + bdf);
      float gg = tanh_(gb[s_nl][256 + u_nl] + bdg);
      float og = sig_ (gb[s_nl][384 + u_nl] + bdo);
      c_reg = fg * c_reg + ig * gg;
      float hh = og * tanh_(c_reg);
      ((uint8_t*)&hb8[s_nl][0])[u_nl] = f8_(hh);
      ((_Float16*)&dech2[s_nl][t][0])[u_nl] = (_Float16)hh;
    }
    __syncthreads();
  }

  // ----------------- fused head -----------------
  {
    int j = tid & 63, w = tid >> 6;
    float acc[8];
    #pragma unroll
    for (int m = 0; m < 8; ++m) acc[m] = b1[j];
    #pragma unroll 8
    for (int k = 0; k < 64; ++k) {
      uint32_t wv = W1h[k*64 + j];
      #pragma unroll
      for (int m = 0; m < 8; ++m) {
        int st = w + 8*m;
        acc[m] = fdot2_(wv, dech2[st >> 5][st & 31][k], acc[m]);
      }
    }
    #pragma unroll
    for (int m = 0; m < 8; ++m) {
      int st = w + 8*m;
      hidf[st][j] = fmaxf(acc[m], 0.0f);
    }
  }
  __syncthreads();
  if (tid < 128) {
    int st = tid >> 1, e = tid & 1;
    float acc = b2[e];
    #pragma unroll 16
    for (int j = 0; j < 64; ++j) acc += W2[e*64 + j] * hidf[st][j];
    int s = st >> 5, t = st & 31;
    out_kp[((bn0 + s)*32 + t)*2 + e] = acc;
  }
}

// ---------------------------------------------------------------------------
// Launch
// ---------------------------------------------------------------------------
extern "C" void kernel_launch(void* const* d_in, const int* in_sizes, int n_in,
                              void* d_out, int out_size, void* d_ws, size_t ws_size,
                              hipStream_t stream) {
  const float* x          = (const float*)d_in[0];
  const float* mask_point = (const float*)d_in[1];
  const int*   point_mask = (const int*)d_in[2];
  const float* conv1_w    = (const float*)d_in[3];
  const float* conv1_b    = (const float*)d_in[4];
  const float* conv2_w    = (const float*)d_in[5];
  const float* conv2_b    = (const float*)d_in[6];
  const float* Wih_e      = (const float*)d_in[7];
  const float* Whh_e      = (const float*)d_in[8];
  const float* bih_e      = (const float*)d_in[9];
  const float* bhh_e      = (const float*)d_in[10];
  const float* Wih_d      = (const float*)d_in[11];
  const float* Whh_d      = (const float*)d_in[12];
  const float* bih_d      = (const float*)d_in[13];
  const float* bhh_d      = (const float*)d_in[14];
  const float* W1         = (const float*)d_in[15];
  const float* b1         = (const float*)d_in[16];
  const float* W2         = (const float*)d_in[17];
  const float* b2         = (const float*)d_in[18];

  float* out = (float*)d_out;
  char*  ws  = (char*)d_ws;

  const bool use_xt = (ws_size >= WS_NEED_XT);

  prep_kernel<<<(PREP_TOTAL + 255)/256, 256, 0, stream>>>(
      Wih_e, Whh_e, bih_e, bhh_e, Wih_d, Whh_d, bih_d, bhh_d,
      conv1_w, conv2_w, W1, mask_point, out + 32768, (int*)(ws + OFF_FLAT),
      ws, use_xt ? 1 : 0);

  if (use_xt) {
    transpose_kernel<<<1024, 256, 0, stream>>>(x, (uint32_t*)(ws + OFF_XT));
    conv_mfma_kernel<<<256, 512, 0, stream>>>(
        (const uint32_t*)(ws + OFF_XT), point_mask, conv1_b, conv2_b,
        ws, (_Float16*)(ws + OFF_DOTS), (const int*)(ws + OFF_FLAT));
  } else {
    conv_gather_kernel<<<512, 256, 0, stream>>>(
        x, point_mask, conv1_b, conv2_b,
        ws, (_Float16*)(ws + OFF_DOTS), (const int*)(ws + OFF_FLAT));
  }

  lstm_head_kernel<<<256, 512, 0, stream>>>(ws, b1, W2, b2, out);
}

// Round 16
// 106.056 us; speedup vs baseline: 1.5921x; 1.1437x over previous
//
#include <hip/hip_runtime.h>
#include <stdint.h>

// ---------------------------------------------------------------------------
// Problem constants
// ---------------------------------------------------------------------------
#define NSEQ 512        // B*N
#define HIDN 128

// ws byte offsets
#define OFF_FEIH   0                            // enc Wih f16 frags, 64 KB
#define OFF_BIAS_E 65536                        // 512 f32
#define OFF_BIAS_D 67584                        // 512 f32
#define OFF_W1P    69632                        // conv w1 f16 pairs [288][64] (fallback)
#define OFF_W2P    143360                       // conv w2 f16 pairs [32][64] (fallback)
#define OFF_FLAT   151552                       // [16384] int
#define OFF_W1H    217088                       // head W1 f16 pairs [64][64]
#define OFF_FEHH   233472                       // enc Whh f16 frags, 128 KB
#define OFF_FDIH8  364544                       // dec Wih fp8 frags, 64 KB
#define OFF_FDHH8  430080                       // dec Whh fp8 frags, 64 KB
#define OFF_W2T    495616                       // conv w2 frags [64][36] u32
#define OFF_W1F8   504832                       // conv w1 fp8 x16 [64][144] u32
#define OFF_DOTS   (1024*1024)                  // [32][512][64] f16 = 2 MB
#define OFF_XT     (4*1024*1024)                // xT fp8 NHWC = 16.8 MB
#define WS_NEED_XT ((size_t)(4*1024*1024) + (size_t)16*128*128*64 + 1024)

typedef _Float16 h2f __attribute__((ext_vector_type(2)));
typedef _Float16 f16x8 __attribute__((ext_vector_type(8)));
typedef float    f32x4 __attribute__((ext_vector_type(4)));

static __device__ __forceinline__ h2f u2h(uint32_t u) {
  union { uint32_t u; h2f h; } v; v.u = u; return v.h;
}

#if __has_builtin(__builtin_amdgcn_fdot2)
static __device__ __forceinline__ float fdot2_(uint32_t a, uint32_t b, float c) {
  return __builtin_amdgcn_fdot2(u2h(a), u2h(b), c, false);
}
#else
static __device__ __forceinline__ float fdot2_(uint32_t a, uint32_t b, float c) {
  h2f x = u2h(a), y = u2h(b);
  return c + (float)x.x * (float)y.x + (float)x.y * (float)y.y;
}
#endif

static __device__ __forceinline__ uint32_t packh(float a, float b) {
  union { _Float16 h[2]; uint32_t u; } v;
  v.h[0] = (_Float16)a; v.h[1] = (_Float16)b; return v.u;
}
static __device__ __forceinline__ float sig_(float x) {
  return 1.0f / (1.0f + __expf(-x));
}
static __device__ __forceinline__ float tanh_(float x) {
  return 1.0f - 2.0f / (1.0f + __expf(2.0f * x));
}

// ---- fp8 e4m3fn helpers ----------------------------------------------------
static __device__ __forceinline__ uint32_t f2e4m3_sw(float f) {
  union { float f; uint32_t u; } v; v.f = f;
  uint32_t s = (v.u >> 24) & 0x80u;
  float af = fabsf(f);
  if (af == 0.0f) return s;
  if (af >= 448.0f) return s | 0x7Eu;
  int e; float m = frexpf(af, &e);
  int E = e + 6;
  float mant = m * 2.0f - 1.0f;
  int mm = (int)(mant * 8.0f + 0.5f);
  if (mm == 8) { mm = 0; ++E; }
  if (E < 1) {
    int sm = (int)(af * 512.0f + 0.5f);
    return s | (uint32_t)(sm > 7 ? 7 : sm);
  }
  if (E > 15) return s | 0x7Eu;
  return s | ((uint32_t)E << 3) | (uint32_t)mm;
}
static __device__ __forceinline__ uint32_t pk4_fp8(float a, float b, float c, float d) {
#if __has_builtin(__builtin_amdgcn_cvt_pk_fp8_f32)
  int r = __builtin_amdgcn_cvt_pk_fp8_f32(a, b, 0, false);
  r = __builtin_amdgcn_cvt_pk_fp8_f32(c, d, r, true);
  return (uint32_t)r;
#else
  return f2e4m3_sw(a) | (f2e4m3_sw(b) << 8) | (f2e4m3_sw(c) << 16) | (f2e4m3_sw(d) << 24);
#endif
}
static __device__ __forceinline__ uint8_t f8_(float v) {
#if __has_builtin(__builtin_amdgcn_cvt_pk_fp8_f32)
  return (uint8_t)(__builtin_amdgcn_cvt_pk_fp8_f32(v, 0.f, 0, false) & 0xFF);
#else
  return (uint8_t)f2e4m3_sw(v);
#endif
}
static __device__ __forceinline__ long u2l(uint2 v) {
  union { uint2 v; long l; } x; x.v = v; return x.l;
}
// pinned 8B load (asm-produced -> non-rematerializable)
static __device__ __forceinline__ uint2 ldg_frag8(const uint2* p) {
  uint2 r;
  asm volatile("global_load_dwordx2 %0, %1, off" : "=v"(r) : "v"(p));
  return r;
}
static __device__ __forceinline__ void frag_fence() {
  asm volatile("s_waitcnt vmcnt(0)" ::: "memory");
  __builtin_amdgcn_sched_barrier(0);
}

// ---------------------------------------------------------------------------
// prep body (shared by standalone prep_kernel and merged transpose_prep).
// f16 A-frag (16x16x32): lane l holds A[row=l&15][k=(l>>4)*8+j].
// fp8 frags: same map with 8 fp8 bytes.
// conv w1 fp8: byte index i = tap*64 + cin, value x16 (rescaled after conv1).
// ---------------------------------------------------------------------------
static __device__ void prep_body(int idx,
    const float* Wih_e, const float* Whh_e,
    const float* bih_e, const float* bhh_e,
    const float* Wih_d, const float* Whh_d,
    const float* bih_d, const float* bhh_d,
    const float* w1, const float* w2, const float* W1,
    const float* mask_point, float* out_gt, int* flat,
    char* ws, int w1_order) {
  float*    bias_e = (float*)(ws + OFF_BIAS_E);
  float*    bias_d = (float*)(ws + OFF_BIAS_D);
  uint32_t* w1p    = (uint32_t*)(ws + OFF_W1P);
  uint32_t* w2p    = (uint32_t*)(ws + OFF_W2P);
  uint32_t* W1h    = (uint32_t*)(ws + OFF_W1H);
  uint32_t* w2t    = (uint32_t*)(ws + OFF_W2T);
  uint32_t* w1f8   = (uint32_t*)(ws + OFF_W1F8);

  if (idx < 16384) {                              // feih
    int j2 = idx & 3, lane = (idx >> 2) & 63, kt = (idx >> 8) & 1, gt = idx >> 9;
    int g = gt*16 + (lane & 15);
    int k = kt*32 + ((lane >> 4) & 3)*8 + 2*j2;
    ((uint32_t*)(ws + OFF_FEIH))[idx] = packh(Wih_e[g*64 + k], Wih_e[g*64 + k + 1]);
    return;
  }
  idx -= 16384;
  if (idx < 512) { bias_e[idx] = bih_e[idx] + bhh_e[idx]; return; }
  idx -= 512;
  if (idx < 512) { bias_d[idx] = bih_d[idx] + bhh_d[idx]; return; }
  idx -= 512;
  if (idx < 288*64) {                             // conv w1 f16 pairs (fallback)
    int i2 = idx >> 6, c = idx & 63;
    if (w1_order) {
      int tap = i2 >> 5, cin = (i2 & 31) * 2;
      w1p[idx] = packh(w1[c*576 + cin*9 + tap], w1[c*576 + (cin+1)*9 + tap]);
    } else {
      w1p[idx] = packh(w1[c*576 + 2*i2], w1[c*576 + 2*i2 + 1]);
    }
    return;
  }
  idx -= 288*64;
  if (idx < 32*64) {                              // conv w2 pairs (fallback)
    int c2 = idx >> 6, d = idx & 63;
    w2p[idx] = packh(w2[d*64 + 2*c2], w2[d*64 + 2*c2 + 1]);
    return;
  }
  idx -= 32*64;
  if (idx < 64*64) {                              // head W1 pairs
    int k2 = idx >> 6, j = idx & 63;
    W1h[idx] = packh(W1[j*128 + 2*k2], W1[j*128 + 2*k2 + 1]);
    return;
  }
  idx -= 64*64;
  if (idx < 32768) {                              // fehh f16 frags
    int j2 = idx & 3, lane = (idx >> 2) & 63, kt = (idx >> 8) & 3, gt = idx >> 10;
    int g = gt*16 + (lane & 15);
    int k = kt*32 + ((lane >> 4) & 3)*8 + 2*j2;
    ((uint32_t*)(ws + OFF_FEHH))[idx] = packh(Whh_e[g*128 + k], Whh_e[g*128 + k + 1]);
    return;
  }
  idx -= 32768;
  if (idx < 16384) {                              // fdih8 fp8 frags
    int half = idx & 1, lane = (idx >> 1) & 63, kt = (idx >> 7) & 3, gt = idx >> 9;
    int g = gt*16 + (lane & 15);
    int kb = kt*32 + ((lane >> 4) & 3)*8 + half*4;
    const float* W = Wih_d;
    ((uint32_t*)(ws + OFF_FDIH8))[(((gt*4 + kt)*64 + lane) << 1) | half] =
        pk4_fp8(W[g*128 + kb], W[g*128 + kb + 1], W[g*128 + kb + 2], W[g*128 + kb + 3]);
    return;
  }
  idx -= 16384;
  if (idx < 16384) {                              // fdhh8 fp8 frags
    int half = idx & 1, lane = (idx >> 1) & 63, kt = (idx >> 7) & 3, gt = idx >> 9;
    int g = gt*16 + (lane & 15);
    int kb = kt*32 + ((lane >> 4) & 3)*8 + half*4;
    const float* W = Whh_d;
    ((uint32_t*)(ws + OFF_FDHH8))[(((gt*4 + kt)*64 + lane) << 1) | half] =
        pk4_fp8(W[g*128 + kb], W[g*128 + kb + 1], W[g*128 + kb + 2], W[g*128 + kb + 3]);
    return;
  }
  idx -= 16384;
  if (idx < 64*36) {                              // w2t [d][c2] pad 36
    int d = idx / 36, c2 = idx - (idx/36)*36;
    w2t[idx] = (c2 < 32) ? packh(w2[d*64 + 2*c2], w2[d*64 + 2*c2 + 1]) : 0u;
    return;
  }
  idx -= 64*36;
  if (idx < 64*144) {                             // w1 fp8 x16: [c][144] u32
    int c = idx / 144, j = idx - (idx/144)*144;
    int tap = j >> 4, cin0 = (j & 15) * 4;
    w1f8[idx] = pk4_fp8(w1[c*576 + (cin0+0)*9 + tap] * 16.0f,
                        w1[c*576 + (cin0+1)*9 + tap] * 16.0f,
                        w1[c*576 + (cin0+2)*9 + tap] * 16.0f,
                        w1[c*576 + (cin0+3)*9 + tap] * 16.0f);
    return;
  }
  idx -= 64*144;
  if (idx < 16384) {                              // point math -> gt + flat
    float mx = mask_point[idx*2 + 0];
    float my = mask_point[idx*2 + 1];
    float fx = fminf(mx * 0.25f, 127.0f);
    float fy = fminf(my * 0.25f, 127.0f);
    out_gt[idx*2 + 0] = fx * 4.0f;
    out_gt[idx*2 + 1] = fy * 4.0f;
    flat[idx] = (int)(__fmaf_rn(fy, 128.0f, fx));
    return;
  }
}
#define PREP_TOTAL (16384 + 512 + 512 + 288*64 + 32*64 + 64*64 + 32768 + 16384 + 16384 + 64*36 + 64*144 + 16384)
#define PREP_BLOCKS ((PREP_TOTAL + 255) / 256)

__global__ __launch_bounds__(256) void prep_kernel(
    const float* Wih_e, const float* Whh_e, const float* bih_e, const float* bhh_e,
    const float* Wih_d, const float* Whh_d, const float* bih_d, const float* bhh_d,
    const float* w1, const float* w2, const float* W1,
    const float* mask_point, float* out_gt, int* flat, char* ws, int w1_order) {
  prep_body(blockIdx.x * 256 + threadIdx.x,
            Wih_e, Whh_e, bih_e, bhh_e, Wih_d, Whh_d, bih_d, bhh_d,
            w1, w2, W1, mask_point, out_gt, flat, ws, w1_order);
}

// ---------------------------------------------------------------------------
// Merged kernel: blocks 0..1023 = transpose x -> xT fp8 NHWC; rest = prep.
// ---------------------------------------------------------------------------
__global__ __launch_bounds__(256, 2) void transpose_prep_kernel(
    const float* x, uint32_t* xT8,
    const float* Wih_e, const float* Whh_e, const float* bih_e, const float* bhh_e,
    const float* Wih_d, const float* Whh_d, const float* bih_d, const float* bhh_d,
    const float* w1, const float* w2, const float* W1,
    const float* mask_point, float* out_gt, int* flat, char* ws) {
  __shared__ float lds[64][257];
  int bid = blockIdx.x;
  if (bid >= 1024) {
    prep_body((bid - 1024) * 256 + threadIdx.x,
              Wih_e, Whh_e, bih_e, bhh_e, Wih_d, Whh_d, bih_d, bhh_d,
              w1, w2, W1, mask_point, out_gt, flat, ws, 1);
    return;
  }
  int xt = bid & 3, yt = (bid >> 2) & 15, b = bid >> 6;
  int x0 = xt * 32, y0 = yt * 8;
  int tx = threadIdx.x & 31, ty = threadIdx.x >> 5;
  #pragma unroll 8
  for (int c = 0; c < 64; ++c)
    lds[c][ty*32 + tx] = x[((b*64 + c)*128 + (y0 + ty))*128 + (x0 + tx)];
  __syncthreads();
  #pragma unroll 8
  for (int r = 0; r < 16; ++r) {
    int i = threadIdx.x + 256*r;    // i = pos*16 + c4 over 4096
    int c4 = i & 15, pos = i >> 4;
    int yy = pos >> 5, xx = pos & 31;
    uint32_t v = pk4_fp8(lds[c4*4+0][pos], lds[c4*4+1][pos],
                         lds[c4*4+2][pos], lds[c4*4+3][pos]);
    xT8[((b*128 + y0 + yy)*128 + (x0 + xx))*16 + c4] = v;
  }
}

// ---------------------------------------------------------------------------
// Kernel 2 (fp8 MFMA): gathered conv (3x3 -> ReLU -> 1x1) at points.
// 256 blocks x 512 threads (8 waves, 2 blocks/CU); 64 points/block, 2 iters.
// conv1: fp8 MFMA, 18 k-tiles K=32 (w1 x16, output /16 folded into ReLU).
// conv2: f16 MFMA, 2 k-tiles (unchanged from R14).
// LDS: w1s8 [64][146]u32 (37.4K), patch8 [32][146]u32 (18.7K), t1s 4.6K = 61K.
// ---------------------------------------------------------------------------
__global__ __launch_bounds__(512, 2) void conv_mfma8_kernel(
    const uint32_t* xT8, const int* point_mask,
    const float* conv1_b, const float* conv2_b,
    const char* ws_ro, _Float16* dots_h, const int* flat) {
  __shared__ __attribute__((aligned(16))) uint32_t w1s8[64*146];   // 37376 B
  __shared__ __attribute__((aligned(16))) uint32_t patch8[32*146]; // 18688 B
  __shared__ __attribute__((aligned(16))) uint32_t t1s[32*36];     //  4608 B

  const uint32_t* w1f8 = (const uint32_t*)(ws_ro + OFF_W1F8);
  const uint32_t* w2t  = (const uint32_t*)(ws_ro + OFF_W2T);
  int tid  = threadIdx.x;
  int lane = tid & 63, wave = tid >> 6;
  int r = wave & 3, g = wave >> 2;      // channel-tile, point-group
  int cl = lane & 15, lgrp = lane >> 4;

  #pragma unroll
  for (int i = tid; i < 64*144; i += 512) {
    int c = i / 144, j = i - c*144;
    w1s8[c*146 + j] = w1f8[i];
  }

  // conv2 A-frags (f16, in registers)
  uint4 a2[2];
  #pragma unroll
  for (int kt = 0; kt < 2; ++kt)
    a2[kt] = *(const uint4*)&w2t[(r*16 + cl)*36 + kt*16 + lgrp*4];

  float4 b1r = *(const float4*)&conv1_b[r*16 + lgrp*4];
  float4 b2v = *(const float4*)&conv2_b[r*16 + lgrp*4];
  f32x4 b1v = {b1r.x*16.f, b1r.y*16.f, b1r.z*16.f, b1r.w*16.f};

  for (int it = 0; it < 2; ++it) {
    int p0 = blockIdx.x * 64 + it * 32;
    __syncthreads();                    // patch8/t1s reuse (+ w1s8 ready, it=0)
    #pragma unroll
    for (int rr = 0; rr < 9; ++rr) {    // 4608 u32 = 32 slots x 144
      int u = tid + 512*rr;
      int slot = u / 144, j = u - slot*144;
      int tap = j >> 4, c4 = j & 15;
      int p = p0 + slot;
      int fl = flat[p];
      int hh = fl >> 7, ww = fl & 127;
      int b = p >> 10;
      int dy = tap / 3, dx = tap - dy*3;
      int yy = hh + dy - 1, xx = ww + dx - 1;
      uint32_t v = 0u;
      if (yy >= 0 && yy < 128 && xx >= 0 && xx < 128)
        v = xT8[((b*128 + yy)*128 + xx)*16 + c4];
      patch8[slot*146 + j] = v;
    }
    __syncthreads();

    // conv1 fp8 MFMA: 18 k-tiles (K=32 bytes each)
    f32x4 acc = b1v;
    #pragma unroll
    for (int kt = 0; kt < 18; ++kt) {
      long af = u2l(*(const uint2*)&w1s8[(r*16 + cl)*146 + kt*8 + lgrp*2]);
      long bf = u2l(*(const uint2*)&patch8[(g*16 + cl)*146 + kt*8 + lgrp*2]);
      acc = __builtin_amdgcn_mfma_f32_16x16x32_fp8_fp8(af, bf, acc, 0, 0, 0);
    }
    // relu + rescale (/16) -> t1 (f16)
    {
      int trow = (g*16 + cl)*36 + r*8 + lgrp*2;
      t1s[trow]     = packh(fmaxf(acc[0], 0.f) * 0.0625f, fmaxf(acc[1], 0.f) * 0.0625f);
      t1s[trow + 1] = packh(fmaxf(acc[2], 0.f) * 0.0625f, fmaxf(acc[3], 0.f) * 0.0625f);
    }
    __syncthreads();

    // conv2 f16 MFMA: 2 k-tiles
    f32x4 acc2 = {b2v.x, b2v.y, b2v.z, b2v.w};
    #pragma unroll
    for (int kt = 0; kt < 2; ++kt) {
      f16x8 af; __builtin_memcpy(&af, &a2[kt], 16);
      f16x8 bf = *(const f16x8*)&t1s[(g*16 + cl)*36 + kt*16 + lgrp*4];
      acc2 = __builtin_amdgcn_mfma_f32_16x16x32_f16(af, bf, acc2, 0, 0, 0);
    }
    {
      int p = p0 + g*16 + cl;
      float m = (float)point_mask[p];
      int kk = p & 31, bn = p >> 5;
      int d0 = r*16 + lgrp*4;
      uint2 o;
      o.x = packh(acc2[0]*m, acc2[1]*m);
      o.y = packh(acc2[2]*m, acc2[3]*m);
      *(uint2*)&dots_h[(size_t)(kk*NSEQ + bn)*64 + d0] = o;
    }
  }
}

// ---------------------------------------------------------------------------
// Kernel 2 fallback (no xT): scalar gathered conv from NCHW f32 (f16 math).
// ---------------------------------------------------------------------------
__global__ __launch_bounds__(256, 2) void conv_gather_kernel(
    const float* x, const int* point_mask,
    const float* conv1_b, const float* conv2_b,
    const char* ws_ro, _Float16* dots_h, const int* flat) {
  __shared__ uint32_t w1s[64*292];
  __shared__ uint32_t patch2[4*288];
  __shared__ uint32_t tl2[4*32];

  const uint32_t* w1p = (const uint32_t*)(ws_ro + OFF_W1P);
  const uint32_t* w2p = (const uint32_t*)(ws_ro + OFF_W2P);
  int tid = threadIdx.x;
  for (int i = tid; i < 288*64; i += 256) {
    int i2 = i >> 6, cc = i & 63;
    w1s[cc*292 + i2] = w1p[i];
  }

  int q = tid >> 6, c = tid & 63;
  float c1b = conv1_b[c], c2b = conv2_b[c];

  for (int g = 0; g < 8; ++g) {
    int p0 = blockIdx.x * 32 + g * 4;
    __syncthreads();
    #pragma unroll
    for (int r = 0; r < 9; ++r) {
      int l = tid + 256*r;
      int slot = l / 576;
      int within = l - slot*576;
      int cp = within / 9;
      int tap = within - cp*9;
      int p = p0 + slot;
      int fl = flat[p];
      int hh = fl >> 7, ww = fl & 127;
      int b = p >> 10;
      int yy = hh + tap/3 - 1, xx = ww + tap%3 - 1;
      float v = 0.0f;
      if (yy >= 0 && yy < 128 && xx >= 0 && xx < 128)
        v = x[((b*64 + cp)*128 + yy)*128 + xx];
      ((_Float16*)patch2)[l] = (_Float16)v;
    }
    __syncthreads();

    float a0 = c1b, a1 = 0.f, a2 = 0.f, a3 = 0.f;
    int cbase = c * 292, pbase = q * 288;
    #pragma unroll 4
    for (int i2 = 0; i2 < 288; i2 += 4) {
      // NOTE: fallback uses w1_order=1 packing (tap*32+c2) on both sides
      a0 = fdot2_(w1s[cbase + i2+0], patch2[pbase + i2+0], a0);
      a1 = fdot2_(w1s[cbase + i2+1], patch2[pbase + i2+1], a1);
      a2 = fdot2_(w1s[cbase + i2+2], patch2[pbase + i2+2], a2);
      a3 = fdot2_(w1s[cbase + i2+3], patch2[pbase + i2+3], a3);
    }
    float t1 = fmaxf((a0 + a1) + (a2 + a3), 0.0f);
    ((_Float16*)tl2)[q*64 + c] = (_Float16)t1;

    float acc2 = c2b;
    #pragma unroll
    for (int c2i = 0; c2i < 32; ++c2i)
      acc2 = fdot2_(w2p[c2i*64 + c], tl2[q*32 + c2i], acc2);
    int p = p0 + q;
    acc2 *= (float)point_mask[p];
    int k = p & 31, bn = p >> 5;
    dots_h[(k*NSEQ + bn)*64 + c] = (_Float16)acc2;
  }
}

// ---------------------------------------------------------------------------
// Kernel 3: recurrent LSTMs via MFMA (gb-roundtrip dedup nonlinearity) +
// fused MLP head. 256 blocks x 512 threads; 2 seqs/block.
// Encoder: f16 MFMA with fused x-projection; decoder: fp8 MFMA.
// ---------------------------------------------------------------------------
__global__ __launch_bounds__(512, 2) void lstm_head_kernel(
    const char* ws_ro,
    const float* b1, const float* W2, const float* b2,
    float* out_kp) {
  const f16x8* feih   = (const f16x8*)(ws_ro + OFF_FEIH);
  const f16x8* fehh   = (const f16x8*)(ws_ro + OFF_FEHH);
  const uint2* fdih8  = (const uint2*)(ws_ro + OFF_FDIH8);
  const uint2* fdhh8  = (const uint2*)(ws_ro + OFF_FDHH8);
  const float* bias_e = (const float*)(ws_ro + OFF_BIAS_E);
  const float* bias_d = (const float*)(ws_ro + OFF_BIAS_D);
  const uint32_t* dots_u = (const uint32_t*)(ws_ro + OFF_DOTS);
  const uint32_t* W1h = (const uint32_t*)(ws_ro + OFF_W1H);

  __shared__ __attribute__((aligned(16))) uint32_t xs[2][32][32];     //  8 KB
  __shared__ __attribute__((aligned(16))) uint32_t enc8[2][32][32];   //  8 KB
  __shared__ __attribute__((aligned(16))) uint32_t dech2[2][32][64];  // 16 KB
  __shared__ __attribute__((aligned(16))) uint32_t hb2[2][64];        // 512 B
  __shared__ __attribute__((aligned(16))) uint32_t hb8[2][32];        // 256 B
  __shared__ __attribute__((aligned(16))) float    gb[2][512];        //  4 KB
  __shared__ float hidf[64][65];                                      // 16.6 KB

  int tid  = threadIdx.x;
  int lane = tid & 63, wave = tid >> 6;
  int col  = lane & 15, lgrp = lane >> 4;
  int sb   = col & 1;
  int bn0  = blockIdx.x * 2;

  int s_nl = tid >> 7, u_nl = tid & 127;
  float c_reg = 0.0f;

  for (int i = tid; i < 2048; i += 512) {
    int s = i >> 10, rem = i & 1023, t = rem >> 5, k2 = rem & 31;
    xs[s][t][k2] = dots_u[(t*NSEQ + bn0 + s)*32 + k2];
  }

  f16x8 ax[4][2], ae[4][4];
  #pragma unroll
  for (int g0 = 0; g0 < 4; ++g0) {
    #pragma unroll
    for (int kt = 0; kt < 2; ++kt)
      ax[g0][kt] = feih[((wave*4 + g0)*2 + kt)*64 + lane];
    #pragma unroll
    for (int kt = 0; kt < 4; ++kt)
      ae[g0][kt] = fehh[((wave*4 + g0)*4 + kt)*64 + lane];
  }

  float be0 = bias_e[u_nl],       be1 = bias_e[128 + u_nl];
  float be2 = bias_e[256 + u_nl], be3 = bias_e[384 + u_nl];

  if (tid < 128) hb2[tid >> 6][tid & 63] = 0u;
  __syncthreads();

  const f16x8 bzero = {};

  // ----------------- encoder -----------------
  for (int t = 0; t < 32; ++t) {
    f16x8 bx[2], bf[4];
    #pragma unroll
    for (int kt = 0; kt < 2; ++kt)
      bx[kt] = *(const f16x8*)&xs[sb][t][kt*16 + lgrp*4];
    #pragma unroll
    for (int kt = 0; kt < 4; ++kt) {
      if (col < 2) bf[kt] = *(const f16x8*)&hb2[col][kt*16 + lgrp*4];
      else         bf[kt] = bzero;
    }
    #pragma unroll
    for (int g0 = 0; g0 < 4; ++g0) {
      f32x4 acc = {0.f, 0.f, 0.f, 0.f};
      #pragma unroll
      for (int kt = 0; kt < 2; ++kt)
        acc = __builtin_amdgcn_mfma_f32_16x16x32_f16(ax[g0][kt], bx[kt], acc, 0, 0, 0);
      #pragma unroll
      for (int kt = 0; kt < 4; ++kt)
        acc = __builtin_amdgcn_mfma_f32_16x16x32_f16(ae[g0][kt], bf[kt], acc, 0, 0, 0);
      if (col < 2)
        *(f32x4*)&gb[col][(wave*4 + g0)*16 + lgrp*4] = acc;
    }
    __syncthreads();
    if (tid < 256) {
      float ig = sig_ (gb[s_nl][u_nl]       + be0);
      float fg = sig_ (gb[s_nl][128 + u_nl] + be1);
      float gg = tanh_(gb[s_nl][256 + u_nl] + be2);
      float og = sig_ (gb[s_nl][384 + u_nl] + be3);
      c_reg = fg * c_reg + ig * gg;
      float hh = og * tanh_(c_reg);
      ((_Float16*)&hb2[s_nl][0])[u_nl] = (_Float16)hh;
      ((uint8_t*)&enc8[s_nl][t][0])[u_nl] = f8_(hh);
    }
    __syncthreads();
  }

  if (tid < 256) {
    float hv = (float)((_Float16*)&hb2[s_nl][0])[u_nl];
    ((uint8_t*)&hb8[s_nl][0])[u_nl] = f8_(hv);
  }

  uint2 dih8[4][4], dhh8[4][4];
  #pragma unroll
  for (int g0 = 0; g0 < 4; ++g0)
    #pragma unroll
    for (int kt = 0; kt < 4; ++kt) {
      dih8[g0][kt] = ldg_frag8(&fdih8[((wave*4 + g0)*4 + kt)*64 + lane]);
      dhh8[g0][kt] = ldg_frag8(&fdhh8[((wave*4 + g0)*4 + kt)*64 + lane]);
    }
  frag_fence();
  float bdi = 0.f, bdf = 0.f, bdg = 0.f, bdo = 0.f;
  if (tid < 256) {
    bdi = bias_d[u_nl];       bdf = bias_d[128 + u_nl];
    bdg = bias_d[256 + u_nl]; bdo = bias_d[384 + u_nl];
  }
  __syncthreads();

  // ----------------- decoder (fp8 MFMA) -----------------
  for (int t = 0; t < 32; ++t) {
    long bx[4], bh[4];
    #pragma unroll
    for (int kt = 0; kt < 4; ++kt) {
      if (col < 2) {
        bx[kt] = u2l(*(const uint2*)&enc8[col][t][kt*8 + lgrp*2]);
        bh[kt] = u2l(*(const uint2*)&hb8[col][kt*8 + lgrp*2]);
      } else { bx[kt] = 0; bh[kt] = 0; }
    }
    #pragma unroll
    for (int g0 = 0; g0 < 4; ++g0) {
      f32x4 acc = {0.f, 0.f, 0.f, 0.f};
      #pragma unroll
      for (int kt = 0; kt < 4; ++kt)
        acc = __builtin_amdgcn_mfma_f32_16x16x32_fp8_fp8(
            u2l(dih8[g0][kt]), bx[kt], acc, 0, 0, 0);
      #pragma unroll
      for (int kt = 0; kt < 4; ++kt)
        acc = __builtin_amdgcn_mfma_f32_16x16x32_fp8_fp8(
            u2l(dhh8[g0][kt]), bh[kt], acc, 0, 0, 0);
      if (col < 2)
        *(f32x4*)&gb[col][(wave*4 + g0)*16 + lgrp*4] = acc;
    }
    __syncthreads();
    if (tid < 256) {
      float ig = sig_ (gb[s_nl][u_nl]       + bdi);
      float fg = sig_ (gb[s_nl][128 + u_nl] + bdf);
      float gg = tanh_(gb[s_nl][256 + u_nl] + bdg);
      float og = sig_ (gb[s_nl][384 + u_nl] + bdo);
      c_reg = fg * c_reg + ig * gg;
      float hh = og * tanh_(c_reg);
      ((uint8_t*)&hb8[s_nl][0])[u_nl] = f8_(hh);
      ((_Float16*)&dech2[s_nl][t][0])[u_nl] = (_Float16)hh;
    }
    __syncthreads();
  }

  // ----------------- fused head -----------------
  {
    int j = tid & 63, w = tid >> 6;
    float acc[8];
    #pragma unroll
    for (int m = 0; m < 8; ++m) acc[m] = b1[j];
    #pragma unroll 8
    for (int k = 0; k < 64; ++k) {
      uint32_t wv = W1h[k*64 + j];
      #pragma unroll
      for (int m = 0; m < 8; ++m) {
        int st = w + 8*m;
        acc[m] = fdot2_(wv, dech2[st >> 5][st & 31][k], acc[m]);
      }
    }
    #pragma unroll
    for (int m = 0; m < 8; ++m) {
      int st = w + 8*m;
      hidf[st][j] = fmaxf(acc[m], 0.0f);
    }
  }
  __syncthreads();
  if (tid < 128) {
    int st = tid >> 1, e = tid & 1;
    float acc = b2[e];
    #pragma unroll 16
    for (int j = 0; j < 64; ++j) acc += W2[e*64 + j] * hidf[st][j];
    int s = st >> 5, t = st & 31;
    out_kp[((bn0 + s)*32 + t)*2 + e] = acc;
  }
}

// ---------------------------------------------------------------------------
// Launch
// ---------------------------------------------------------------------------
extern "C" void kernel_launch(void* const* d_in, const int* in_sizes, int n_in,
                              void* d_out, int out_size, void* d_ws, size_t ws_size,
                              hipStream_t stream) {
  const float* x          = (const float*)d_in[0];
  const float* mask_point = (const float*)d_in[1];
  const int*   point_mask = (const int*)d_in[2];
  const float* conv1_w    = (const float*)d_in[3];
  const float* conv1_b    = (const float*)d_in[4];
  const float* conv2_w    = (const float*)d_in[5];
  const float* conv2_b    = (const float*)d_in[6];
  const float* Wih_e      = (const float*)d_in[7];
  const float* Whh_e      = (const float*)d_in[8];
  const float* bih_e      = (const float*)d_in[9];
  const float* bhh_e      = (const float*)d_in[10];
  const float* Wih_d      = (const float*)d_in[11];
  const float* Whh_d      = (const float*)d_in[12];
  const float* bih_d      = (const float*)d_in[13];
  const float* bhh_d      = (const float*)d_in[14];
  const float* W1         = (const float*)d_in[15];
  const float* b1         = (const float*)d_in[16];
  const float* W2         = (const float*)d_in[17];
  const float* b2         = (const float*)d_in[18];

  float* out = (float*)d_out;
  char*  ws  = (char*)d_ws;

  const bool use_xt = (ws_size >= WS_NEED_XT);

  if (use_xt) {
    transpose_prep_kernel<<<1024 + PREP_BLOCKS, 256, 0, stream>>>(
        x, (uint32_t*)(ws + OFF_XT),
        Wih_e, Whh_e, bih_e, bhh_e, Wih_d, Whh_d, bih_d, bhh_d,
        conv1_w, conv2_w, W1, mask_point, out + 32768, (int*)(ws + OFF_FLAT), ws);
    conv_mfma8_kernel<<<256, 512, 0, stream>>>(
        (const uint32_t*)(ws + OFF_XT), point_mask, conv1_b, conv2_b,
        ws, (_Float16*)(ws + OFF_DOTS), (const int*)(ws + OFF_FLAT));
  } else {
    prep_kernel<<<PREP_BLOCKS, 256, 0, stream>>>(
        Wih_e, Whh_e, bih_e, bhh_e, Wih_d, Whh_d, bih_d, bhh_d,
        conv1_w, conv2_w, W1, mask_point, out + 32768, (int*)(ws + OFF_FLAT),
        ws, 1);
    conv_gather_kernel<<<512, 256, 0, stream>>>(
        x, point_mask, conv1_b, conv2_b,
        ws, (_Float16*)(ws + OFF_DOTS), (const int*)(ws + OFF_FLAT));
  }

  lstm_head_kernel<<<256, 512, 0, stream>>>(ws, b1, W2, b2, out);
}

// Round 17
// 103.453 us; speedup vs baseline: 1.6321x; 1.0252x over previous
//
#include <hip/hip_runtime.h>
#include <stdint.h>

// ---------------------------------------------------------------------------
// Problem constants
// ---------------------------------------------------------------------------
#define NSEQ 512        // B*N
#define HIDN 128

// ws byte offsets
#define OFF_FEIH   0                            // enc Wih f16 frags, 64 KB
#define OFF_BIAS_E 65536                        // 512 f32
#define OFF_BIAS_D 67584                        // 512 f32
#define OFF_W1P    69632                        // conv w1 f16 pairs [288][64] (fallback)
#define OFF_W2P    143360                       // conv w2 f16 pairs [32][64] (fallback)
#define OFF_FLAT   151552                       // [16384] int
#define OFF_W1H    217088                       // head W1 f16 pairs [64][64]
#define OFF_FEHH   233472                       // enc Whh f16 frags, 128 KB
#define OFF_FDIH8  364544                       // dec Wih fp8 frags, 64 KB
#define OFF_FDHH8  430080                       // dec Whh fp8 frags, 64 KB
#define OFF_W2T    495616                       // conv w2 frags [64][36] u32
#define OFF_W1F8   504832                       // conv w1 fp8 x16 [64][144] u32
#define OFF_DOTS   (1024*1024)                  // fallback dots buffer
#define OFF_XT     (4*1024*1024)                // xT fp8 NHWC = 16.8 MB
#define WS_NEED_XT ((size_t)(4*1024*1024) + (size_t)16*128*128*64 + 1024)

typedef _Float16 h2f __attribute__((ext_vector_type(2)));
typedef _Float16 f16x8 __attribute__((ext_vector_type(8)));
typedef float    f32x4 __attribute__((ext_vector_type(4)));

static __device__ __forceinline__ h2f u2h(uint32_t u) {
  union { uint32_t u; h2f h; } v; v.u = u; return v.h;
}

#if __has_builtin(__builtin_amdgcn_fdot2)
static __device__ __forceinline__ float fdot2_(uint32_t a, uint32_t b, float c) {
  return __builtin_amdgcn_fdot2(u2h(a), u2h(b), c, false);
}
#else
static __device__ __forceinline__ float fdot2_(uint32_t a, uint32_t b, float c) {
  h2f x = u2h(a), y = u2h(b);
  return c + (float)x.x * (float)y.x + (float)x.y * (float)y.y;
}
#endif

static __device__ __forceinline__ uint32_t packh(float a, float b) {
  union { _Float16 h[2]; uint32_t u; } v;
  v.h[0] = (_Float16)a; v.h[1] = (_Float16)b; return v.u;
}
static __device__ __forceinline__ float sig_(float x) {
  return 1.0f / (1.0f + __expf(-x));
}
static __device__ __forceinline__ float tanh_(float x) {
  return 1.0f - 2.0f / (1.0f + __expf(2.0f * x));
}

// ---- fp8 e4m3fn helpers ----------------------------------------------------
static __device__ __forceinline__ uint32_t f2e4m3_sw(float f) {
  union { float f; uint32_t u; } v; v.f = f;
  uint32_t s = (v.u >> 24) & 0x80u;
  float af = fabsf(f);
  if (af == 0.0f) return s;
  if (af >= 448.0f) return s | 0x7Eu;
  int e; float m = frexpf(af, &e);
  int E = e + 6;
  float mant = m * 2.0f - 1.0f;
  int mm = (int)(mant * 8.0f + 0.5f);
  if (mm == 8) { mm = 0; ++E; }
  if (E < 1) {
    int sm = (int)(af * 512.0f + 0.5f);
    return s | (uint32_t)(sm > 7 ? 7 : sm);
  }
  if (E > 15) return s | 0x7Eu;
  return s | ((uint32_t)E << 3) | (uint32_t)mm;
}
static __device__ __forceinline__ uint32_t pk4_fp8(float a, float b, float c, float d) {
#if __has_builtin(__builtin_amdgcn_cvt_pk_fp8_f32)
  int r = __builtin_amdgcn_cvt_pk_fp8_f32(a, b, 0, false);
  r = __builtin_amdgcn_cvt_pk_fp8_f32(c, d, r, true);
  return (uint32_t)r;
#else
  return f2e4m3_sw(a) | (f2e4m3_sw(b) << 8) | (f2e4m3_sw(c) << 16) | (f2e4m3_sw(d) << 24);
#endif
}
static __device__ __forceinline__ uint8_t f8_(float v) {
#if __has_builtin(__builtin_amdgcn_cvt_pk_fp8_f32)
  return (uint8_t)(__builtin_amdgcn_cvt_pk_fp8_f32(v, 0.f, 0, false) & 0xFF);
#else
  return (uint8_t)f2e4m3_sw(v);
#endif
}
static __device__ __forceinline__ long u2l(uint2 v) {
  union { uint2 v; long l; } x; x.v = v; return x.l;
}
// pinned 8B load (asm-produced -> non-rematerializable)
static __device__ __forceinline__ uint2 ldg_frag8(const uint2* p) {
  uint2 r;
  asm volatile("global_load_dwordx2 %0, %1, off" : "=v"(r) : "v"(p));
  return r;
}
static __device__ __forceinline__ void frag_fence() {
  asm volatile("s_waitcnt vmcnt(0)" ::: "memory");
  __builtin_amdgcn_sched_barrier(0);
}

// ---------------------------------------------------------------------------
// prep body (shared by standalone prep_kernel and merged transpose_prep).
// ---------------------------------------------------------------------------
static __device__ void prep_body(int idx,
    const float* Wih_e, const float* Whh_e,
    const float* bih_e, const float* bhh_e,
    const float* Wih_d, const float* Whh_d,
    const float* bih_d, const float* bhh_d,
    const float* w1, const float* w2, const float* W1,
    const float* mask_point, float* out_gt, int* flat,
    char* ws, int w1_order) {
  float*    bias_e = (float*)(ws + OFF_BIAS_E);
  float*    bias_d = (float*)(ws + OFF_BIAS_D);
  uint32_t* w1p    = (uint32_t*)(ws + OFF_W1P);
  uint32_t* w2p    = (uint32_t*)(ws + OFF_W2P);
  uint32_t* W1h    = (uint32_t*)(ws + OFF_W1H);
  uint32_t* w2t    = (uint32_t*)(ws + OFF_W2T);
  uint32_t* w1f8   = (uint32_t*)(ws + OFF_W1F8);

  if (idx < 16384) {                              // feih
    int j2 = idx & 3, lane = (idx >> 2) & 63, kt = (idx >> 8) & 1, gt = idx >> 9;
    int g = gt*16 + (lane & 15);
    int k = kt*32 + ((lane >> 4) & 3)*8 + 2*j2;
    ((uint32_t*)(ws + OFF_FEIH))[idx] = packh(Wih_e[g*64 + k], Wih_e[g*64 + k + 1]);
    return;
  }
  idx -= 16384;
  if (idx < 512) { bias_e[idx] = bih_e[idx] + bhh_e[idx]; return; }
  idx -= 512;
  if (idx < 512) { bias_d[idx] = bih_d[idx] + bhh_d[idx]; return; }
  idx -= 512;
  if (idx < 288*64) {                             // conv w1 f16 pairs (fallback)
    int i2 = idx >> 6, c = idx & 63;
    if (w1_order) {
      int tap = i2 >> 5, cin = (i2 & 31) * 2;
      w1p[idx] = packh(w1[c*576 + cin*9 + tap], w1[c*576 + (cin+1)*9 + tap]);
    } else {
      w1p[idx] = packh(w1[c*576 + 2*i2], w1[c*576 + 2*i2 + 1]);
    }
    return;
  }
  idx -= 288*64;
  if (idx < 32*64) {                              // conv w2 pairs (fallback)
    int c2 = idx >> 6, d = idx & 63;
    w2p[idx] = packh(w2[d*64 + 2*c2], w2[d*64 + 2*c2 + 1]);
    return;
  }
  idx -= 32*64;
  if (idx < 64*64) {                              // head W1 pairs
    int k2 = idx >> 6, j = idx & 63;
    W1h[idx] = packh(W1[j*128 + 2*k2], W1[j*128 + 2*k2 + 1]);
    return;
  }
  idx -= 64*64;
  if (idx < 32768) {                              // fehh f16 frags
    int j2 = idx & 3, lane = (idx >> 2) & 63, kt = (idx >> 8) & 3, gt = idx >> 10;
    int g = gt*16 + (lane & 15);
    int k = kt*32 + ((lane >> 4) & 3)*8 + 2*j2;
    ((uint32_t*)(ws + OFF_FEHH))[idx] = packh(Whh_e[g*128 + k], Whh_e[g*128 + k + 1]);
    return;
  }
  idx -= 32768;
  if (idx < 16384) {                              // fdih8 fp8 frags
    int half = idx & 1, lane = (idx >> 1) & 63, kt = (idx >> 7) & 3, gt = idx >> 9;
    int g = gt*16 + (lane & 15);
    int kb = kt*32 + ((lane >> 4) & 3)*8 + half*4;
    const float* W = Wih_d;
    ((uint32_t*)(ws + OFF_FDIH8))[(((gt*4 + kt)*64 + lane) << 1) | half] =
        pk4_fp8(W[g*128 + kb], W[g*128 + kb + 1], W[g*128 + kb + 2], W[g*128 + kb + 3]);
    return;
  }
  idx -= 16384;
  if (idx < 16384) {                              // fdhh8 fp8 frags
    int half = idx & 1, lane = (idx >> 1) & 63, kt = (idx >> 7) & 3, gt = idx >> 9;
    int g = gt*16 + (lane & 15);
    int kb = kt*32 + ((lane >> 4) & 3)*8 + half*4;
    const float* W = Whh_d;
    ((uint32_t*)(ws + OFF_FDHH8))[(((gt*4 + kt)*64 + lane) << 1) | half] =
        pk4_fp8(W[g*128 + kb], W[g*128 + kb + 1], W[g*128 + kb + 2], W[g*128 + kb + 3]);
    return;
  }
  idx -= 16384;
  if (idx < 64*36) {                              // w2t [d][c2] pad 36
    int d = idx / 36, c2 = idx - (idx/36)*36;
    w2t[idx] = (c2 < 32) ? packh(w2[d*64 + 2*c2], w2[d*64 + 2*c2 + 1]) : 0u;
    return;
  }
  idx -= 64*36;
  if (idx < 64*144) {                             // w1 fp8 x16: [c][144] u32
    int c = idx / 144, j = idx - (idx/144)*144;
    int tap = j >> 4, cin0 = (j & 15) * 4;
    w1f8[idx] = pk4_fp8(w1[c*576 + (cin0+0)*9 + tap] * 16.0f,
                        w1[c*576 + (cin0+1)*9 + tap] * 16.0f,
                        w1[c*576 + (cin0+2)*9 + tap] * 16.0f,
                        w1[c*576 + (cin0+3)*9 + tap] * 16.0f);
    return;
  }
  idx -= 64*144;
  if (idx < 16384) {                              // point math -> gt + flat
    float mx = mask_point[idx*2 + 0];
    float my = mask_point[idx*2 + 1];
    float fx = fminf(mx * 0.25f, 127.0f);
    float fy = fminf(my * 0.25f, 127.0f);
    out_gt[idx*2 + 0] = fx * 4.0f;
    out_gt[idx*2 + 1] = fy * 4.0f;
    flat[idx] = (int)(__fmaf_rn(fy, 128.0f, fx));
    return;
  }
}
#define PREP_TOTAL (16384 + 512 + 512 + 288*64 + 32*64 + 64*64 + 32768 + 16384 + 16384 + 64*36 + 64*144 + 16384)
#define PREP_BLOCKS ((PREP_TOTAL + 255) / 256)

__global__ __launch_bounds__(256) void prep_kernel(
    const float* Wih_e, const float* Whh_e, const float* bih_e, const float* bhh_e,
    const float* Wih_d, const float* Whh_d, const float* bih_d, const float* bhh_d,
    const float* w1, const float* w2, const float* W1,
    const float* mask_point, float* out_gt, int* flat, char* ws, int w1_order) {
  prep_body(blockIdx.x * 256 + threadIdx.x,
            Wih_e, Whh_e, bih_e, bhh_e, Wih_d, Whh_d, bih_d, bhh_d,
            w1, w2, W1, mask_point, out_gt, flat, ws, w1_order);
}

// ---------------------------------------------------------------------------
// Merged kernel: blocks 0..1023 = transpose x -> xT fp8 NHWC; rest = prep.
// ---------------------------------------------------------------------------
__global__ __launch_bounds__(256, 2) void transpose_prep_kernel(
    const float* x, uint32_t* xT8,
    const float* Wih_e, const float* Whh_e, const float* bih_e, const float* bhh_e,
    const float* Wih_d, const float* Whh_d, const float* bih_d, const float* bhh_d,
    const float* w1, const float* w2, const float* W1,
    const float* mask_point, float* out_gt, int* flat, char* ws) {
  __shared__ float lds[64][257];
  int bid = blockIdx.x;
  if (bid >= 1024) {
    prep_body((bid - 1024) * 256 + threadIdx.x,
              Wih_e, Whh_e, bih_e, bhh_e, Wih_d, Whh_d, bih_d, bhh_d,
              w1, w2, W1, mask_point, out_gt, flat, ws, 1);
    return;
  }
  int xt = bid & 3, yt = (bid >> 2) & 15, b = bid >> 6;
  int x0 = xt * 32, y0 = yt * 8;
  int tx = threadIdx.x & 31, ty = threadIdx.x >> 5;
  #pragma unroll 8
  for (int c = 0; c < 64; ++c)
    lds[c][ty*32 + tx] = x[((b*64 + c)*128 + (y0 + ty))*128 + (x0 + tx)];
  __syncthreads();
  #pragma unroll 8
  for (int r = 0; r < 16; ++r) {
    int i = threadIdx.x + 256*r;    // i = pos*16 + c4 over 4096
    int c4 = i & 15, pos = i >> 4;
    int yy = pos >> 5, xx = pos & 31;
    uint32_t v = pk4_fp8(lds[c4*4+0][pos], lds[c4*4+1][pos],
                         lds[c4*4+2][pos], lds[c4*4+3][pos]);
    xT8[((b*128 + y0 + yy)*128 + (x0 + xx))*16 + c4] = v;
  }
}

// ---------------------------------------------------------------------------
// MERGED conv + LSTM + head. 256 blocks x 512 threads (8 waves); block bid
// owns seqs {2bid, 2bid+1} = points [64bid, 64bid+64) -- exactly the points
// whose conv outputs it consumes. Conv writes xs LDS directly (no dots
// global roundtrip). smem region: conv {w1s8,patch8,t1s} 60.7KB, reused by
// {dech2,hidf} after conv. Total LDS 80KB.
// Conv: fp8 MFMA (w1 x16, /16 at ReLU) + f16 conv2.
// Encoder: f16 MFMA, fused x-proj. Decoder: fp8 MFMA. Head: fdot2.
// ---------------------------------------------------------------------------
#define SM_W1S8   0        // 64*146 u32 = 37376
#define SM_PATCH  37376    // 32*146 u32 = 18688
#define SM_T1S    56064    // 32*36 u32  =  4608  (end 60672)
#define SM_DECH2  0        // 2*32*64 u32 = 16384 (after conv)
#define SM_HIDF   16384    // 64*65 f32 = 16640   (end 33024)
#define SM_BYTES  60672

__global__ __launch_bounds__(512, 2) void conv_lstm_kernel(
    const uint32_t* xT8, const int* point_mask,
    const float* conv1_b, const float* conv2_b,
    const char* ws_ro, const int* flat,
    const float* b1, const float* W2, const float* b2,
    float* out_kp) {
  __shared__ __attribute__((aligned(16))) char smem[SM_BYTES];        // 60672
  __shared__ __attribute__((aligned(16))) uint32_t xs[2][32][32];     //  8 KB
  __shared__ __attribute__((aligned(16))) uint32_t enc8[2][32][32];   //  8 KB
  __shared__ __attribute__((aligned(16))) uint32_t hb2[2][64];        // 512 B
  __shared__ __attribute__((aligned(16))) uint32_t hb8[2][32];        // 256 B
  __shared__ __attribute__((aligned(16))) float    gb[2][512];        //  4 KB

  const f16x8* feih   = (const f16x8*)(ws_ro + OFF_FEIH);
  const f16x8* fehh   = (const f16x8*)(ws_ro + OFF_FEHH);
  const uint2* fdih8  = (const uint2*)(ws_ro + OFF_FDIH8);
  const uint2* fdhh8  = (const uint2*)(ws_ro + OFF_FDHH8);
  const float* bias_e = (const float*)(ws_ro + OFF_BIAS_E);
  const float* bias_d = (const float*)(ws_ro + OFF_BIAS_D);
  const uint32_t* W1h = (const uint32_t*)(ws_ro + OFF_W1H);
  const uint32_t* w1f8 = (const uint32_t*)(ws_ro + OFF_W1F8);
  const uint32_t* w2t  = (const uint32_t*)(ws_ro + OFF_W2T);

  int tid  = threadIdx.x;
  int lane = tid & 63, wave = tid >> 6;
  int cl = lane & 15, lgrp = lane >> 4;

  // =========================== conv phase ===========================
  {
    uint32_t* w1s8   = (uint32_t*)(smem + SM_W1S8);
    uint32_t* patch8 = (uint32_t*)(smem + SM_PATCH);
    uint32_t* t1s    = (uint32_t*)(smem + SM_T1S);
    int r = wave & 3, g = wave >> 2;    // channel-tile, point-group

    #pragma unroll
    for (int i = tid; i < 64*144; i += 512) {
      int c = i / 144, j = i - c*144;
      w1s8[c*146 + j] = w1f8[i];
    }

    uint4 a2[2];
    #pragma unroll
    for (int kt = 0; kt < 2; ++kt)
      a2[kt] = *(const uint4*)&w2t[(r*16 + cl)*36 + kt*16 + lgrp*4];

    float4 b1r = *(const float4*)&conv1_b[r*16 + lgrp*4];
    float4 b2v = *(const float4*)&conv2_b[r*16 + lgrp*4];
    f32x4 b1v = {b1r.x*16.f, b1r.y*16.f, b1r.z*16.f, b1r.w*16.f};

    for (int it = 0; it < 2; ++it) {
      int p0 = blockIdx.x * 64 + it * 32;
      __syncthreads();                  // patch8/t1s reuse (+ w1s8 ready, it=0)
      #pragma unroll
      for (int rr = 0; rr < 9; ++rr) {  // 4608 u32 = 32 slots x 144
        int u = tid + 512*rr;
        int slot = u / 144, j = u - slot*144;
        int tap = j >> 4, c4 = j & 15;
        int p = p0 + slot;
        int fl = flat[p];
        int hh = fl >> 7, ww = fl & 127;
        int b = p >> 10;
        int dy = tap / 3, dx = tap - dy*3;
        int yy = hh + dy - 1, xx = ww + dx - 1;
        uint32_t v = 0u;
        if (yy >= 0 && yy < 128 && xx >= 0 && xx < 128)
          v = xT8[((b*128 + yy)*128 + xx)*16 + c4];
        patch8[slot*146 + j] = v;
      }
      __syncthreads();

      f32x4 acc = b1v;
      #pragma unroll
      for (int kt = 0; kt < 18; ++kt) {
        long af = u2l(*(const uint2*)&w1s8[(r*16 + cl)*146 + kt*8 + lgrp*2]);
        long bf = u2l(*(const uint2*)&patch8[(g*16 + cl)*146 + kt*8 + lgrp*2]);
        acc = __builtin_amdgcn_mfma_f32_16x16x32_fp8_fp8(af, bf, acc, 0, 0, 0);
      }
      {
        int trow = (g*16 + cl)*36 + r*8 + lgrp*2;
        t1s[trow]     = packh(fmaxf(acc[0], 0.f) * 0.0625f, fmaxf(acc[1], 0.f) * 0.0625f);
        t1s[trow + 1] = packh(fmaxf(acc[2], 0.f) * 0.0625f, fmaxf(acc[3], 0.f) * 0.0625f);
      }
      __syncthreads();

      f32x4 acc2 = {b2v.x, b2v.y, b2v.z, b2v.w};
      #pragma unroll
      for (int kt = 0; kt < 2; ++kt) {
        f16x8 af; __builtin_memcpy(&af, &a2[kt], 16);
        f16x8 bf = *(const f16x8*)&t1s[(g*16 + cl)*36 + kt*16 + lgrp*4];
        acc2 = __builtin_amdgcn_mfma_f32_16x16x32_f16(af, bf, acc2, 0, 0, 0);
      }
      {
        int p = p0 + g*16 + cl;             // t = p&31 = g*16+cl, seq = it
        float m = (float)point_mask[p];
        uint2 o;
        o.x = packh(acc2[0]*m, acc2[1]*m);
        o.y = packh(acc2[2]*m, acc2[3]*m);
        *(uint2*)&xs[it][g*16 + cl][r*8 + lgrp*2] = o;   // direct to LDS!
      }
    }
  }
  __syncthreads();   // conv region dead; xs ready

  // =========================== LSTM phase ===========================
  uint32_t* dech2 = (uint32_t*)(smem + SM_DECH2);   // [2][32][64] u32
  float*    hidf  = (float*)(smem + SM_HIDF);       // [64][65]

  int col = cl;                      // MFMA B col
  int sb  = col & 1;
  int bn0 = blockIdx.x * 2;
  int s_nl = tid >> 7, u_nl = tid & 127;
  float c_reg = 0.0f;

  f16x8 ax[4][2], ae[4][4];
  #pragma unroll
  for (int g0 = 0; g0 < 4; ++g0) {
    #pragma unroll
    for (int kt = 0; kt < 2; ++kt)
      ax[g0][kt] = feih[((wave*4 + g0)*2 + kt)*64 + lane];
    #pragma unroll
    for (int kt = 0; kt < 4; ++kt)
      ae[g0][kt] = fehh[((wave*4 + g0)*4 + kt)*64 + lane];
  }

  float be0 = bias_e[u_nl],       be1 = bias_e[128 + u_nl];
  float be2 = bias_e[256 + u_nl], be3 = bias_e[384 + u_nl];

  if (tid < 128) hb2[tid >> 6][tid & 63] = 0u;
  __syncthreads();

  const f16x8 bzero = {};

  // ----------------- encoder -----------------
  for (int t = 0; t < 32; ++t) {
    f16x8 bx[2], bf[4];
    #pragma unroll
    for (int kt = 0; kt < 2; ++kt)
      bx[kt] = *(const f16x8*)&xs[sb][t][kt*16 + lgrp*4];
    #pragma unroll
    for (int kt = 0; kt < 4; ++kt) {
      if (col < 2) bf[kt] = *(const f16x8*)&hb2[col][kt*16 + lgrp*4];
      else         bf[kt] = bzero;
    }
    #pragma unroll
    for (int g0 = 0; g0 < 4; ++g0) {
      f32x4 acc = {0.f, 0.f, 0.f, 0.f};
      #pragma unroll
      for (int kt = 0; kt < 2; ++kt)
        acc = __builtin_amdgcn_mfma_f32_16x16x32_f16(ax[g0][kt], bx[kt], acc, 0, 0, 0);
      #pragma unroll
      for (int kt = 0; kt < 4; ++kt)
        acc = __builtin_amdgcn_mfma_f32_16x16x32_f16(ae[g0][kt], bf[kt], acc, 0, 0, 0);
      if (col < 2)
        *(f32x4*)&gb[col][(wave*4 + g0)*16 + lgrp*4] = acc;
    }
    __syncthreads();
    if (tid < 256) {
      float ig = sig_ (gb[s_nl][u_nl]       + be0);
      float fg = sig_ (gb[s_nl][128 + u_nl] + be1);
      float gg = tanh_(gb[s_nl][256 + u_nl] + be2);
      float og = sig_ (gb[s_nl][384 + u_nl] + be3);
      c_reg = fg * c_reg + ig * gg;
      float hh = og * tanh_(c_reg);
      ((_Float16*)&hb2[s_nl][0])[u_nl] = (_Float16)hh;
      ((uint8_t*)&enc8[s_nl][t][0])[u_nl] = f8_(hh);
    }
    __syncthreads();
  }

  if (tid < 256) {
    float hv = (float)((_Float16*)&hb2[s_nl][0])[u_nl];
    ((uint8_t*)&hb8[s_nl][0])[u_nl] = f8_(hv);
  }

  uint2 dih8[4][4], dhh8[4][4];
  #pragma unroll
  for (int g0 = 0; g0 < 4; ++g0)
    #pragma unroll
    for (int kt = 0; kt < 4; ++kt) {
      dih8[g0][kt] = ldg_frag8(&fdih8[((wave*4 + g0)*4 + kt)*64 + lane]);
      dhh8[g0][kt] = ldg_frag8(&fdhh8[((wave*4 + g0)*4 + kt)*64 + lane]);
    }
  frag_fence();
  float bdi = 0.f, bdf = 0.f, bdg = 0.f, bdo = 0.f;
  if (tid < 256) {
    bdi = bias_d[u_nl];       bdf = bias_d[128 + u_nl];
    bdg = bias_d[256 + u_nl]; bdo = bias_d[384 + u_nl];
  }
  __syncthreads();

  // ----------------- decoder (fp8 MFMA) -----------------
  for (int t = 0; t < 32; ++t) {
    long bx[4], bh[4];
    #pragma unroll
    for (int kt = 0; kt < 4; ++kt) {
      if (col < 2) {
        bx[kt] = u2l(*(const uint2*)&enc8[col][t][kt*8 + lgrp*2]);
        bh[kt] = u2l(*(const uint2*)&hb8[col][kt*8 + lgrp*2]);
      } else { bx[kt] = 0; bh[kt] = 0; }
    }
    #pragma unroll
    for (int g0 = 0; g0 < 4; ++g0) {
      f32x4 acc = {0.f, 0.f, 0.f, 0.f};
      #pragma unroll
      for (int kt = 0; kt < 4; ++kt)
        acc = __builtin_amdgcn_mfma_f32_16x16x32_fp8_fp8(
            u2l(dih8[g0][kt]), bx[kt], acc, 0, 0, 0);
      #pragma unroll
      for (int kt = 0; kt < 4; ++kt)
        acc = __builtin_amdgcn_mfma_f32_16x16x32_fp8_fp8(
            u2l(dhh8[g0][kt]), bh[kt], acc, 0, 0, 0);
      if (col < 2)
        *(f32x4*)&gb[col][(wave*4 + g0)*16 + lgrp*4] = acc;
    }
    __syncthreads();
    if (tid < 256) {
      float ig = sig_ (gb[s_nl][u_nl]       + bdi);
      float fg = sig_ (gb[s_nl][128 + u_nl] + bdf);
      float gg = tanh_(gb[s_nl][256 + u_nl] + bdg);
      float og = sig_ (gb[s_nl][384 + u_nl] + bdo);
      c_reg = fg * c_reg + ig * gg;
      float hh = og * tanh_(c_reg);
      ((uint8_t*)&hb8[s_nl][0])[u_nl] = f8_(hh);
      ((_Float16*)&dech2[(s_nl*32 + t)*64])[u_nl] = (_Float16)hh;
    }
    __syncthreads();
  }

  // ----------------- fused head -----------------
  {
    int j = tid & 63, w = tid >> 6;
    float acc[8];
    #pragma unroll
    for (int m = 0; m < 8; ++m) acc[m] = b1[j];
    #pragma unroll 8
    for (int k = 0; k < 64; ++k) {
      uint32_t wv = W1h[k*64 + j];
      #pragma unroll
      for (int m = 0; m < 8; ++m) {
        int st = w + 8*m;
        acc[m] = fdot2_(wv, dech2[st*64 + k], acc[m]);
      }
    }
    #pragma unroll
    for (int m = 0; m < 8; ++m) {
      int st = w + 8*m;
      hidf[st*65 + j] = fmaxf(acc[m], 0.0f);
    }
  }
  __syncthreads();
  if (tid < 128) {
    int st = tid >> 1, e = tid & 1;
    float acc = b2[e];
    #pragma unroll 16
    for (int j = 0; j < 64; ++j) acc += W2[e*64 + j] * hidf[st*65 + j];
    int s = st >> 5, t = st & 31;
    out_kp[((bn0 + s)*32 + t)*2 + e] = acc;
  }
}

// ---------------------------------------------------------------------------
// Fallback kernels (no xT): scalar conv from NCHW f32 + lstm reading dots.
// ---------------------------------------------------------------------------
__global__ __launch_bounds__(256, 2) void conv_gather_kernel(
    const float* x, const int* point_mask,
    const float* conv1_b, const float* conv2_b,
    const char* ws_ro, _Float16* dots_h, const int* flat) {
  __shared__ uint32_t w1s[64*292];
  __shared__ uint32_t patch2[4*288];
  __shared__ uint32_t tl2[4*32];

  const uint32_t* w1p = (const uint32_t*)(ws_ro + OFF_W1P);
  const uint32_t* w2p = (const uint32_t*)(ws_ro + OFF_W2P);
  int tid = threadIdx.x;
  for (int i = tid; i < 288*64; i += 256) {
    int i2 = i >> 6, cc = i & 63;
    w1s[cc*292 + i2] = w1p[i];
  }

  int q = tid >> 6, c = tid & 63;
  float c1b = conv1_b[c], c2b = conv2_b[c];

  for (int g = 0; g < 8; ++g) {
    int p0 = blockIdx.x * 32 + g * 4;
    __syncthreads();
    #pragma unroll
    for (int r = 0; r < 9; ++r) {
      int l = tid + 256*r;
      int slot = l / 576;
      int within = l - slot*576;
      int cp = within / 9;
      int tap = within - cp*9;
      int p = p0 + slot;
      int fl = flat[p];
      int hh = fl >> 7, ww = fl & 127;
      int b = p >> 10;
      int yy = hh + tap/3 - 1, xx = ww + tap%3 - 1;
      float v = 0.0f;
      if (yy >= 0 && yy < 128 && xx >= 0 && xx < 128)
        v = x[((b*64 + cp)*128 + yy)*128 + xx];
      ((_Float16*)patch2)[l] = (_Float16)v;
    }
    __syncthreads();

    float a0 = c1b, a1 = 0.f, a2 = 0.f, a3 = 0.f;
    int cbase = c * 292, pbase = q * 288;
    #pragma unroll 4
    for (int i2 = 0; i2 < 288; i2 += 4) {
      a0 = fdot2_(w1s[cbase + i2+0], patch2[pbase + i2+0], a0);
      a1 = fdot2_(w1s[cbase + i2+1], patch2[pbase + i2+1], a1);
      a2 = fdot2_(w1s[cbase + i2+2], patch2[pbase + i2+2], a2);
      a3 = fdot2_(w1s[cbase + i2+3], patch2[pbase + i2+3], a3);
    }
    float t1 = fmaxf((a0 + a1) + (a2 + a3), 0.0f);
    ((_Float16*)tl2)[q*64 + c] = (_Float16)t1;

    float acc2 = c2b;
    #pragma unroll
    for (int c2i = 0; c2i < 32; ++c2i)
      acc2 = fdot2_(w2p[c2i*64 + c], tl2[q*32 + c2i], acc2);
    int p = p0 + q;
    acc2 *= (float)point_mask[p];
    int k = p & 31, bn = p >> 5;
    dots_h[(k*NSEQ + bn)*64 + c] = (_Float16)acc2;
  }
}

__global__ __launch_bounds__(512, 2) void lstm_head_fb_kernel(
    const char* ws_ro,
    const float* b1, const float* W2, const float* b2,
    float* out_kp) {
  const f16x8* feih   = (const f16x8*)(ws_ro + OFF_FEIH);
  const f16x8* fehh   = (const f16x8*)(ws_ro + OFF_FEHH);
  const uint2* fdih8  = (const uint2*)(ws_ro + OFF_FDIH8);
  const uint2* fdhh8  = (const uint2*)(ws_ro + OFF_FDHH8);
  const float* bias_e = (const float*)(ws_ro + OFF_BIAS_E);
  const float* bias_d = (const float*)(ws_ro + OFF_BIAS_D);
  const uint32_t* dots_u = (const uint32_t*)(ws_ro + OFF_DOTS);
  const uint32_t* W1h = (const uint32_t*)(ws_ro + OFF_W1H);

  __shared__ __attribute__((aligned(16))) uint32_t xs[2][32][32];
  __shared__ __attribute__((aligned(16))) uint32_t enc8[2][32][32];
  __shared__ __attribute__((aligned(16))) uint32_t dech2[2][32][64];
  __shared__ __attribute__((aligned(16))) uint32_t hb2[2][64];
  __shared__ __attribute__((aligned(16))) uint32_t hb8[2][32];
  __shared__ __attribute__((aligned(16))) float    gb[2][512];
  __shared__ float hidf[64][65];

  int tid  = threadIdx.x;
  int lane = tid & 63, wave = tid >> 6;
  int col  = lane & 15, lgrp = lane >> 4;
  int sb   = col & 1;
  int bn0  = blockIdx.x * 2;
  int s_nl = tid >> 7, u_nl = tid & 127;
  float c_reg = 0.0f;

  for (int i = tid; i < 2048; i += 512) {
    int s = i >> 10, rem = i & 1023, t = rem >> 5, k2 = rem & 31;
    xs[s][t][k2] = dots_u[(t*NSEQ + bn0 + s)*32 + k2];
  }

  f16x8 ax[4][2], ae[4][4];
  #pragma unroll
  for (int g0 = 0; g0 < 4; ++g0) {
    #pragma unroll
    for (int kt = 0; kt < 2; ++kt)
      ax[g0][kt] = feih[((wave*4 + g0)*2 + kt)*64 + lane];
    #pragma unroll
    for (int kt = 0; kt < 4; ++kt)
      ae[g0][kt] = fehh[((wave*4 + g0)*4 + kt)*64 + lane];
  }

  float be0 = bias_e[u_nl],       be1 = bias_e[128 + u_nl];
  float be2 = bias_e[256 + u_nl], be3 = bias_e[384 + u_nl];

  if (tid < 128) hb2[tid >> 6][tid & 63] = 0u;
  __syncthreads();

  const f16x8 bzero = {};

  for (int t = 0; t < 32; ++t) {
    f16x8 bx[2], bf[4];
    #pragma unroll
    for (int kt = 0; kt < 2; ++kt)
      bx[kt] = *(const f16x8*)&xs[sb][t][kt*16 + lgrp*4];
    #pragma unroll
    for (int kt = 0; kt < 4; ++kt) {
      if (col < 2) bf[kt] = *(const f16x8*)&hb2[col][kt*16 + lgrp*4];
      else         bf[kt] = bzero;
    }
    #pragma unroll
    for (int g0 = 0; g0 < 4; ++g0) {
      f32x4 acc = {0.f, 0.f, 0.f, 0.f};
      #pragma unroll
      for (int kt = 0; kt < 2; ++kt)
        acc = __builtin_amdgcn_mfma_f32_16x16x32_f16(ax[g0][kt], bx[kt], acc, 0, 0, 0);
      #pragma unroll
      for (int kt = 0; kt < 4; ++kt)
        acc = __builtin_amdgcn_mfma_f32_16x16x32_f16(ae[g0][kt], bf[kt], acc, 0, 0, 0);
      if (col < 2)
        *(f32x4*)&gb[col][(wave*4 + g0)*16 + lgrp*4] = acc;
    }
    __syncthreads();
    if (tid < 256) {
      float ig = sig_ (gb[s_nl][u_nl]       + be0);
      float fg = sig_ (gb[s_nl][128 + u_nl] + be1);
      float gg = tanh_(gb[s_nl][256 + u_nl] + be2);
      float og = sig_ (gb[s_nl][384 + u_nl] + be3);
      c_reg = fg * c_reg + ig * gg;
      float hh = og * tanh_(c_reg);
      ((_Float16*)&hb2[s_nl][0])[u_nl] = (_Float16)hh;
      ((uint8_t*)&enc8[s_nl][t][0])[u_nl] = f8_(hh);
    }
    __syncthreads();
  }

  if (tid < 256) {
    float hv = (float)((_Float16*)&hb2[s_nl][0])[u_nl];
    ((uint8_t*)&hb8[s_nl][0])[u_nl] = f8_(hv);
  }

  uint2 dih8[4][4], dhh8[4][4];
  #pragma unroll
  for (int g0 = 0; g0 < 4; ++g0)
    #pragma unroll
    for (int kt = 0; kt < 4; ++kt) {
      dih8[g0][kt] = ldg_frag8(&fdih8[((wave*4 + g0)*4 + kt)*64 + lane]);
      dhh8[g0][kt] = ldg_frag8(&fdhh8[((wave*4 + g0)*4 + kt)*64 + lane]);
    }
  frag_fence();
  float bdi = 0.f, bdf = 0.f, bdg = 0.f, bdo = 0.f;
  if (tid < 256) {
    bdi = bias_d[u_nl];       bdf = bias_d[128 + u_nl];
    bdg = bias_d[256 + u_nl]; bdo = bias_d[384 + u_nl];
  }
  __syncthreads();

  for (int t = 0; t < 32; ++t) {
    long bx[4], bh[4];
    #pragma unroll
    for (int kt = 0; kt < 4; ++kt) {
      if (col < 2) {
        bx[kt] = u2l(*(const uint2*)&enc8[col][t][kt*8 + lgrp*2]);
        bh[kt] = u2l(*(const uint2*)&hb8[col][kt*8 + lgrp*2]);
      } else { bx[kt] = 0; bh[kt] = 0; }
    }
    #pragma unroll
    for (int g0 = 0; g0 < 4; ++g0) {
      f32x4 acc = {0.f, 0.f, 0.f, 0.f};
      #pragma unroll
      for (int kt = 0; kt < 4; ++kt)
        acc = __builtin_amdgcn_mfma_f32_16x16x32_fp8_fp8(
            u2l(dih8[g0][kt]), bx[kt], acc, 0, 0, 0);
      #pragma unroll
      for (int kt = 0; kt < 4; ++kt)
        acc = __builtin_amdgcn_mfma_f32_16x16x32_fp8_fp8(
            u2l(dhh8[g0][kt]), bh[kt], acc, 0, 0, 0);
      if (col < 2)
        *(f32x4*)&gb[col][(wave*4 + g0)*16 + lgrp*4] = acc;
    }
    __syncthreads();
    if (tid < 256) {
      float ig = sig_ (gb[s_nl][u_nl]       + bdi);
      float fg = sig_ (gb[s_nl][128 + u_nl] + bdf);
      float gg = tanh_(gb[s_nl][256 + u_nl] + bdg);
      float og = sig_ (gb[s_nl][384 + u_nl] + bdo);
      c_reg = fg * c_reg + ig * gg;
      float hh = og * tanh_(c_reg);
      ((uint8_t*)&hb8[s_nl][0])[u_nl] = f8_(hh);
      ((_Float16*)&dech2[s_nl][t][0])[u_nl] = (_Float16)hh;
    }
    __syncthreads();
  }

  {
    int j = tid & 63, w = tid >> 6;
    float acc[8];
    #pragma unroll
    for (int m = 0; m < 8; ++m) acc[m] = b1[j];
    #pragma unroll 8
    for (int k = 0; k < 64; ++k) {
      uint32_t wv = W1h[k*64 + j];
      #pragma unroll
      for (int m = 0; m < 8; ++m) {
        int st = w + 8*m;
        acc[m] = fdot2_(wv, dech2[st >> 5][st & 31][k], acc[m]);
      }
    }
    #pragma unroll
    for (int m = 0; m < 8; ++m) {
      int st = w + 8*m;
      hidf[st][j] = fmaxf(acc[m], 0.0f);
    }
  }
  __syncthreads();
  if (tid < 128) {
    int st = tid >> 1, e = tid & 1;
    float acc = b2[e];
    #pragma unroll 16
    for (int j = 0; j < 64; ++j) acc += W2[e*64 + j] * hidf[st][j];
    int s = st >> 5, t = st & 31;
    out_kp[((bn0 + s)*32 + t)*2 + e] = acc;
  }
}

// ---------------------------------------------------------------------------
// Launch
// ---------------------------------------------------------------------------
extern "C" void kernel_launch(void* const* d_in, const int* in_sizes, int n_in,
                              void* d_out, int out_size, void* d_ws, size_t ws_size,
                              hipStream_t stream) {
  const float* x          = (const float*)d_in[0];
  const float* mask_point = (const float*)d_in[1];
  const int*   point_mask = (const int*)d_in[2];
  const float* conv1_w    = (const float*)d_in[3];
  const float* conv1_b    = (const float*)d_in[4];
  const float* conv2_w    = (const float*)d_in[5];
  const float* conv2_b    = (const float*)d_in[6];
  const float* Wih_e      = (const float*)d_in[7];
  const float* Whh_e      = (const float*)d_in[8];
  const float* bih_e      = (const float*)d_in[9];
  const float* bhh_e      = (const float*)d_in[10];
  const float* Wih_d      = (const float*)d_in[11];
  const float* Whh_d      = (const float*)d_in[12];
  const float* bih_d      = (const float*)d_in[13];
  const float* bhh_d      = (const float*)d_in[14];
  const float* W1         = (const float*)d_in[15];
  const float* b1         = (const float*)d_in[16];
  const float* W2         = (const float*)d_in[17];
  const float* b2         = (const float*)d_in[18];

  float* out = (float*)d_out;
  char*  ws  = (char*)d_ws;

  const bool use_xt = (ws_size >= WS_NEED_XT);

  if (use_xt) {
    transpose_prep_kernel<<<1024 + PREP_BLOCKS, 256, 0, stream>>>(
        x, (uint32_t*)(ws + OFF_XT),
        Wih_e, Whh_e, bih_e, bhh_e, Wih_d, Whh_d, bih_d, bhh_d,
        conv1_w, conv2_w, W1, mask_point, out + 32768, (int*)(ws + OFF_FLAT), ws);
    conv_lstm_kernel<<<256, 512, 0, stream>>>(
        (const uint32_t*)(ws + OFF_XT), point_mask, conv1_b, conv2_b,
        ws, (const int*)(ws + OFF_FLAT), b1, W2, b2, out);
  } else {
    prep_kernel<<<PREP_BLOCKS, 256, 0, stream>>>(
        Wih_e, Whh_e, bih_e, bhh_e, Wih_d, Whh_d, bih_d, bhh_d,
        conv1_w, conv2_w, W1, mask_point, out + 32768, (int*)(ws + OFF_FLAT),
        ws, 1);
    conv_gather_kernel<<<512, 256, 0, stream>>>(
        x, point_mask, conv1_b, conv2_b,
        ws, (_Float16*)(ws + OFF_DOTS), (const int*)(ws + OFF_FLAT));
    lstm_head_fb_kernel<<<256, 512, 0, stream>>>(ws, b1, W2, b2, out);
  }
}